// Round 3
// baseline (2369.589 us; speedup 1.0000x reference)
//
#include <hip/hip_runtime.h>
#include <math.h>

#define NPG 100
#define KTOP 60
#define DLAT 97
#define NB 2000         // buckets = graphs
#define NBLK 512        // binning blocks
#define CPB 6250        // edges per binning block = ceil(3.2M/512)

static __device__ __forceinline__ float dot4(float4 a, float4 b){
  return a.x*b.x + a.y*b.y + a.z*b.z + a.w*b.w;
}

// ---------------- prep: atomic-free CSR build via per-graph bucketing ----------------
__global__ __launch_bounds__(256) void k_hist(const int* __restrict__ dst, int* __restrict__ histG, int E){
  __shared__ int h[NB];
  int blk = blockIdx.x, tid = threadIdx.x;
  for(int i=tid;i<NB;i+=256) h[i]=0;
  __syncthreads();
  int e0 = blk*CPB, e1 = min(e0+CPB, E);
  for(int e=e0+tid; e<e1; e+=256) atomicAdd(&h[dst[e]/NPG], 1);
  __syncthreads();
  for(int i=tid;i<NB;i+=256) histG[blk*NB+i] = h[i];
}

__global__ __launch_bounds__(512) void k_colscan(const int* __restrict__ histG,
    int* __restrict__ prefT, int* __restrict__ total){
  __shared__ int s[NBLK];
  int b = blockIdx.x, t = threadIdx.x;
  int v = histG[t*NB + b];
  s[t] = v;
  __syncthreads();
  for(int off=1; off<NBLK; off<<=1){
    int u = (t >= off) ? s[t-off] : 0;
    __syncthreads();
    s[t] += u;
    __syncthreads();
  }
  prefT[b*NBLK + t] = s[t] - v;
  if(t == NBLK-1) total[b] = s[t];
}

__global__ __launch_bounds__(1024) void k_bscan(const int* __restrict__ total, int* __restrict__ bbase){
  __shared__ int s[1024];
  int t = threadIdx.x;
  int i0 = 2*t, i1 = 2*t+1;
  int x0 = (i0 < NB) ? total[i0] : 0;
  int x1 = (i1 < NB) ? total[i1] : 0;
  int ps = x0 + x1;
  s[t] = ps;
  __syncthreads();
  for(int off=1; off<1024; off<<=1){
    int u = (t >= off) ? s[t-off] : 0;
    __syncthreads();
    s[t] += u;
    __syncthreads();
  }
  int excl = s[t] - ps;
  if(i0 < NB) bbase[i0] = excl;
  if(i1 < NB) bbase[i1] = excl + x0;
  if(t == 1023) bbase[NB] = s[1023];
}

// packed edge: x = src | (dst%NPG)<<18  (src<2^18, dstmod<2^7), y = bits of ew
__global__ __launch_bounds__(256) void k_scatter(const int* __restrict__ src, const int* __restrict__ dst,
    const float* __restrict__ ew, const int* __restrict__ prefT, const int* __restrict__ bbase,
    int2* __restrict__ ebuf, int E){
  __shared__ int cur[NB];
  int blk = blockIdx.x, tid = threadIdx.x;
  for(int i=tid;i<NB;i+=256) cur[i] = prefT[i*NBLK + blk] + bbase[i];
  __syncthreads();
  int e0 = blk*CPB, e1 = min(e0+CPB, E);
  for(int e=e0+tid; e<e1; e+=256){
    int d = dst[e];
    int b = d/NPG;
    int dmod = d - b*NPG;
    int pos = atomicAdd(&cur[b], 1);          // LDS atomic
    ebuf[pos] = make_int2(src[e] | (dmod<<18), __float_as_int(ew[e]));
  }
}

__global__ __launch_bounds__(256) void k_bucket(const int2* __restrict__ ebuf, const int* __restrict__ bbase,
    float* __restrict__ dis, int* __restrict__ rs, int2* __restrict__ csr, int N){
  __shared__ float degw[NPG];
  __shared__ int cnt[NPG];
  __shared__ float disl[NPG];
  __shared__ int cur[NPG];
  __shared__ int sc[128];
  int g = blockIdx.x, tid = threadIdx.x;
  int g0 = g*NPG;
  if(tid < NPG){ degw[tid] = 0.f; cnt[tid] = 0; }
  __syncthreads();
  int e0 = bbase[g], e1 = bbase[g+1];
  for(int e=e0+tid; e<e1; e+=256){
    int2 t = ebuf[e];
    int ld = ((unsigned)t.x)>>18;
    atomicAdd(&cnt[ld], 1);
    atomicAdd(&degw[ld], __int_as_float(t.y));
  }
  __syncthreads();
  if(tid < NPG){
    float dv = rsqrtf(degw[tid] + 1.0f);
    disl[tid] = dv;
    dis[g0+tid] = dv;
  }
  if(tid < 128) sc[tid] = (tid < NPG) ? cnt[tid] : 0;
  __syncthreads();
  for(int off=1; off<128; off<<=1){
    int u = 0;
    if(tid < 128 && tid >= off) u = sc[tid-off];
    __syncthreads();
    if(tid < 128) sc[tid] += u;
    __syncthreads();
  }
  if(tid < NPG){
    int st = e0 + sc[tid] - cnt[tid];
    cur[tid] = st;
    rs[g0+tid] = st;
  }
  if(g == NB-1 && tid == 0) rs[N] = e1;
  __syncthreads();
  for(int e=e0+tid; e<e1; e+=256){
    int2 t = ebuf[e];
    int ld = ((unsigned)t.x)>>18;
    int s  = t.x & 0x3FFFF;
    int pos = atomicAdd(&cur[ld], 1);
    csr[pos] = make_int2(s, __float_as_int(__int_as_float(t.y)*disl[ld]));
  }
}

__global__ void k_norm(int2* __restrict__ csr, const float* __restrict__ dis, int E){
  int e = blockIdx.x*256 + threadIdx.x;
  if(e < E){
    int2 p = csr[e];
    p.y = __float_as_int(__int_as_float(p.y)*dis[p.x]);
    csr[e] = p;
  }
}

// ---------------- GEMMs (chunk-major output: hxc[(chunk*N + n)*4 + sub]) ----------------
__global__ __launch_bounds__(256) void k_gemm1(const int* __restrict__ wI, const int* __restrict__ z1I,
   const int* __restrict__ z2I,
   const float* __restrict__ embw, const float* __restrict__ embz1, const float* __restrict__ embz2,
   const float* __restrict__ W0, float* __restrict__ hxc, int N){
  __shared__ __align__(16) float X[128][97];
  __shared__ __align__(16) float Ws[96*32];
  __shared__ int iw[128], i1[128], i2[128];
  int tid = threadIdx.x;
  int g0 = blockIdx.x*128;
  for(int i=tid;i<96*32;i+=256) Ws[i]=W0[i];
  if(tid < 128){
    int gn = g0 + tid;
    bool ok = gn < N;
    iw[tid] = ok ? wI[gn]  : 0;
    i1[tid] = ok ? z1I[gn] : 0;
    i2[tid] = ok ? z2I[gn] : 0;
  }
  __syncthreads();
  for(int r=0;r<48;r++){
    int flat = r*256 + tid;
    int n = flat/96, c = flat - n*96;
    int gn = g0 + n;
    float val = 0.f;
    if(gn < N){
      if(c < 32)      val = embw [iw[n]*32 + c];
      else if(c < 64) val = embz1[i1[n]*32 + (c-32)];
      else            val = embz2[i2[n]*32 + (c-64)];
    }
    X[n][c] = val;
  }
  __syncthreads();
  int ng = tid>>3, chg = tid&7;
  float4 acc[4];
  #pragma unroll
  for(int j=0;j<4;j++) acc[j] = make_float4(0.f,0.f,0.f,0.f);
  #pragma unroll 4
  for(int i=0;i<96;i++){
    float4 wv = *(const float4*)&Ws[i*32 + chg*4];
    #pragma unroll
    for(int j=0;j<4;j++){
      float xv = X[ng*4+j][i];
      acc[j].x += xv*wv.x; acc[j].y += xv*wv.y; acc[j].z += xv*wv.z; acc[j].w += xv*wv.w;
    }
  }
  #pragma unroll
  for(int j=0;j<4;j++){
    int gn = g0 + ng*4 + j;
    if(gn < N) *(float4*)&hxc[((size_t)chg*N + gn)*4] = acc[j];
  }
}

__global__ __launch_bounds__(256) void k_gemm32(const float* __restrict__ xinc, const float* __restrict__ W,
    float* __restrict__ hxc, int N){
  __shared__ __align__(16) float X[128][33];
  __shared__ __align__(16) float Ws[32*32];
  int tid = threadIdx.x;
  int g0 = blockIdx.x*128;
  for(int i=tid;i<1024;i+=256) Ws[i]=W[i];
  for(int r=0;r<16;r++){
    int f = r*256 + tid;
    int chunk = f>>9, rem = f&511, n = rem>>2, sub = rem&3;
    int gn = g0 + n;
    X[n][(chunk<<2)|sub] = (gn < N) ? xinc[((size_t)chunk*N + gn)*4 + sub] : 0.f;
  }
  __syncthreads();
  int ng = tid>>3, chg = tid&7;
  float4 acc[4];
  #pragma unroll
  for(int j=0;j<4;j++) acc[j] = make_float4(0.f,0.f,0.f,0.f);
  #pragma unroll 4
  for(int i=0;i<32;i++){
    float4 wv = *(const float4*)&Ws[i*32 + chg*4];
    #pragma unroll
    for(int j=0;j<4;j++){
      float xv = X[ng*4+j][i];
      acc[j].x += xv*wv.x; acc[j].y += xv*wv.y; acc[j].z += xv*wv.z; acc[j].w += xv*wv.w;
    }
  }
  #pragma unroll
  for(int j=0;j<4;j++){
    int gn = g0 + ng*4 + j;
    if(gn < N) *(float4*)&hxc[((size_t)chg*N + gn)*4] = acc[j];
  }
}

__global__ __launch_bounds__(256) void k_gemmv(const float* __restrict__ xinc, const float* __restrict__ W3,
    float* __restrict__ hv, int N){
  __shared__ float X[256][33];
  __shared__ float Ws[32];
  int tid = threadIdx.x;
  int g0 = blockIdx.x*256;
  if(tid < 32) Ws[tid] = W3[tid];
  for(int r=0;r<32;r++){
    int f = r*256 + tid;
    int chunk = f>>10, rem = f&1023, n = rem>>2, sub = rem&3;
    int gn = g0 + n;
    X[n][(chunk<<2)|sub] = (gn < N) ? xinc[((size_t)chunk*N + gn)*4 + sub] : 0.f;
  }
  __syncthreads();
  float acc = 0.f;
  #pragma unroll
  for(int i=0;i<32;i++) acc += X[tid][i]*Ws[i];
  int gn = g0 + tid;
  if(gn < N) hv[gn] = acc;
}

// ---------------- aggregation: chunk-per-XCD, L2-resident gathers ----------------
__global__ __launch_bounds__(256) void k_agg32c(const float* __restrict__ hxc, const float* __restrict__ dis,
   const int* __restrict__ rs, const int2* __restrict__ csr,
   const float* __restrict__ bias, float* __restrict__ houtc, int N){
  int chunk = blockIdx.x & 7;                 // pins chunk to XCD under round-robin dispatch
  int n = (blockIdx.x >> 3)*256 + threadIdx.x;
  if(n >= N) return;
  const float4* srcv = (const float4*)(hxc + (size_t)chunk*N*4);
  float dn = dis[n];
  float4 h = srcv[n];
  float w0 = dn*dn;
  float4 acc = make_float4(w0*h.x, w0*h.y, w0*h.z, w0*h.w);
  int e0 = rs[n], e1 = rs[n+1];
  for(int e=e0;e<e1;e++){
    int2 p = csr[e];
    float nrm = __int_as_float(p.y);
    float4 v = srcv[p.x];
    acc.x += nrm*v.x; acc.y += nrm*v.y; acc.z += nrm*v.z; acc.w += nrm*v.w;
  }
  float4 bv = *(const float4*)&bias[chunk*4];
  float4 o;
  o.x = tanhf(acc.x + bv.x);
  o.y = tanhf(acc.y + bv.y);
  o.z = tanhf(acc.z + bv.z);
  o.w = tanhf(acc.w + bv.w);
  *(float4*)&houtc[((size_t)chunk*N + n)*4] = o;
}

__global__ void k_agg1(const float* __restrict__ hv, const float* __restrict__ dis,
   const int* __restrict__ rs, const int2* __restrict__ csr,
   const float* __restrict__ b3, float* __restrict__ h4, int N){
  int n = blockIdx.x*256 + threadIdx.x;
  if(n >= N) return;
  float dn = dis[n];
  float acc = dn*dn*hv[n];
  int e0 = rs[n], e1 = rs[n+1];
  for(int e=e0;e<e1;e++){
    int2 p = csr[e];
    acc += __int_as_float(p.y)*hv[p.x];
  }
  h4[n] = tanhf(acc + b3[0]);
}

// ---------------- fused head ----------------
__global__ __launch_bounds__(256) void k_head(const float* __restrict__ h1,const float* __restrict__ h2,
  const float* __restrict__ h3,const float* __restrict__ h4,
  const float* __restrict__ c1W,const float* __restrict__ c1b,
  const float* __restrict__ c2W,const float* __restrict__ c2b,
  const float* __restrict__ l1W,const float* __restrict__ l1b,
  const float* __restrict__ l2W,const float* __restrict__ l2b,
  float* __restrict__ out, int N){
  __shared__ float v[100];
  __shared__ int ord[KTOP];
  __shared__ __align__(16) float xk[KTOP][100];
  __shared__ __align__(16) float c1Ws[16*100];
  __shared__ __align__(16) float t1[16][60];
  __shared__ __align__(16) float t2[16][32];
  __shared__ __align__(16) float c2Ws[32*16*5];
  __shared__ __align__(16) float flat[832];
  __shared__ __align__(16) float o1s[2][128];
  int b = blockIdx.x, tid = threadIdx.x;
  int g0 = b*NPG;
  for(int i=tid;i<16*97;i+=256){ int o=i/97, d=i-o*97; c1Ws[o*100+d]=c1W[i]; }
  for(int i=tid;i<2560;i+=256) c2Ws[i]=c2W[i];
  if(tid < 100) v[tid] = h4[g0+tid];
  __syncthreads();
  if(tid < 100){
    float vi = v[tid];
    int rank = 0;
    for(int j=0;j<100;j++){
      float vj = v[j];
      rank += (vj > vi) || (vj == vi && j < tid);
    }
    if(rank < KTOP) ord[rank] = tid;
  }
  __syncthreads();
  for(int idx=tid; idx<KTOP*DLAT; idx+=256){
    int k = idx/DLAT, d = idx - k*DLAT;
    int n = g0 + ord[k];
    float val;
    if(d < 96){
      const float* hsrc = (d<32) ? h1 : (d<64) ? h2 : h3;
      int dd = d & 31;
      val = hsrc[(((size_t)(dd>>2))*N + n)*4 + (dd&3)];
    } else val = h4[n];
    xk[k][d] = val;
  }
  __syncthreads();
  if(tid < 120){
    int og = tid/15, kg = tid - og*15;
    float a0[4] = {0,0,0,0}, a1[4] = {0,0,0,0};
    for(int d=0; d<96; d+=4){
      float4 w0 = *(const float4*)&c1Ws[og*100 + d];
      float4 w1 = *(const float4*)&c1Ws[(og+8)*100 + d];
      #pragma unroll
      for(int j=0;j<4;j++){
        float4 xv = *(const float4*)&xk[kg + 15*j][d];
        a0[j] += dot4(xv, w0);
        a1[j] += dot4(xv, w1);
      }
    }
    {
      float w0 = c1Ws[og*100 + 96], w1 = c1Ws[(og+8)*100 + 96];
      #pragma unroll
      for(int j=0;j<4;j++){
        float xv = xk[kg + 15*j][96];
        a0[j] += xv*w0;
        a1[j] += xv*w1;
      }
    }
    float b0v = c1b[og], b1v = c1b[og+8];
    #pragma unroll
    for(int j=0;j<4;j++){
      t1[og  ][kg + 15*j] = fmaxf(a0[j] + b0v, 0.f);
      t1[og+8][kg + 15*j] = fmaxf(a1[j] + b1v, 0.f);
    }
  }
  __syncthreads();
  for(int idx=tid; idx<480; idx+=256){
    int o = idx/30, jj = idx - o*30;
    t2[o][jj] = fmaxf(t1[o][2*jj], t1[o][2*jj+1]);
  }
  __syncthreads();
  if(tid < 224){
    int oc = tid/7, pg = tid - oc*7;
    int p0 = pg*4;
    float acc[4] = {0,0,0,0};
    for(int ic=0; ic<16; ic++){
      float4 A  = *(const float4*)&t2[ic][p0];
      float4 Bv = *(const float4*)&t2[ic][p0+4];
      float e[8] = {A.x,A.y,A.z,A.w,Bv.x,Bv.y,Bv.z,Bv.w};
      const float* wr = &c2Ws[(oc*16 + ic)*5];
      #pragma unroll
      for(int q=0;q<4;q++){
        #pragma unroll
        for(int r=0;r<5;r++) acc[q] += e[q+r]*wr[r];
      }
    }
    float bb = c2b[oc];
    #pragma unroll
    for(int q=0;q<4;q++){
      int p = p0 + q;
      if(p < 26) flat[oc*26 + p] = fmaxf(acc[q] + bb, 0.f);
    }
  }
  __syncthreads();
  {
    int half = tid>>7, j = tid&127;
    int i0 = half*416;
    float s = 0.f;
    #pragma unroll 4
    for(int i=0;i<416;i++){
      s += flat[i0+i] * l1W[(size_t)(i0+i)*128 + j];
    }
    o1s[half][j] = s;
  }
  __syncthreads();
  if(tid < 128){
    float r = o1s[0][tid] + o1s[1][tid] + l1b[tid];
    o1s[0][tid] = fmaxf(r, 0.f);
  }
  __syncthreads();
  float* red = (float*)t1;
  if(tid < 128) red[tid] = o1s[0][tid]*l2W[tid];
  __syncthreads();
  if(tid < 64){
    float val = red[tid] + red[tid+64];
    #pragma unroll
    for(int off=32; off>0; off>>=1) val += __shfl_down(val, off);
    if(tid == 0) out[b] = val + l2b[0];
  }
}

// ---------------- launch ----------------
extern "C" void kernel_launch(void* const* d_in, const int* in_sizes, int n_in,
                              void* d_out, int out_size, void* d_ws, size_t ws_size,
                              hipStream_t stream){
  (void)n_in; (void)out_size; (void)ws_size;
  const int*   z1    = (const int*)  d_in[0];
  const int*   z2    = (const int*)  d_in[1];
  const int*   w     = (const int*)  d_in[2];
  const int*   eidx  = (const int*)  d_in[3];
  const float* ew    = (const float*)d_in[5];
  const float* embw  = (const float*)d_in[6];
  const float* embz1 = (const float*)d_in[7];
  const float* embz2 = (const float*)d_in[8];
  const float* W0    = (const float*)d_in[9];
  const float* b0    = (const float*)d_in[10];
  const float* W1    = (const float*)d_in[11];
  const float* b1    = (const float*)d_in[12];
  const float* W2    = (const float*)d_in[13];
  const float* b2    = (const float*)d_in[14];
  const float* W3    = (const float*)d_in[15];
  const float* b3    = (const float*)d_in[16];
  const float* c1W   = (const float*)d_in[17];
  const float* c1b   = (const float*)d_in[18];
  const float* c2W   = (const float*)d_in[19];
  const float* c2b   = (const float*)d_in[20];
  const float* l1W   = (const float*)d_in[21];
  const float* l1b   = (const float*)d_in[22];
  const float* l2W   = (const float*)d_in[23];
  const float* l2b   = (const float*)d_in[24];
  float* out = (float*)d_out;

  int N = in_sizes[0];
  int E = in_sizes[3]/2;
  int B = N/NPG;
  const int* src = eidx;
  const int* dst = eidx + E;

  char* p = (char*)d_ws;
  auto alloc = [&](size_t bytes)->char*{
    char* r = p;
    p += (bytes + 255) & ~(size_t)255;
    return r;
  };
  float* h1c   = (float*)alloc((size_t)N*32*4);
  float* h2c   = (float*)alloc((size_t)N*32*4);
  float* h3c   = (float*)alloc((size_t)N*32*4);
  float* h4    = (float*)alloc((size_t)N*4);
  float* hx    = (float*)alloc((size_t)N*32*4);
  float* dis   = (float*)alloc((size_t)N*4);
  int*   rs    = (int*)  alloc((size_t)(N+1)*4);
  int*   histG = (int*)  alloc((size_t)NBLK*NB*4);
  int*   prefT = (int*)  alloc((size_t)NB*NBLK*4);
  int*   total = (int*)  alloc((size_t)NB*4);
  int*   bbase = (int*)  alloc((size_t)(NB+1)*4);
  int2*  csr   = (int2*) alloc((size_t)E*8);
  int2*  ebuf  = (int2*)h1c;   // alias: 25.6MB fits exactly in h1c; dead before h1c written

  int gE = (E+255)/256;
  k_hist   <<<NBLK, 256, 0, stream>>>(dst, histG, E);
  k_colscan<<<NB,   512, 0, stream>>>(histG, prefT, total);
  k_bscan  <<<1,   1024, 0, stream>>>(total, bbase);
  k_scatter<<<NBLK, 256, 0, stream>>>(src, dst, ew, prefT, bbase, ebuf, E);
  k_bucket <<<B,    256, 0, stream>>>(ebuf, bbase, dis, rs, csr, N);
  k_norm   <<<gE,   256, 0, stream>>>(csr, dis, E);

  int gG = (N+127)/128;
  int gA = 8*((N+255)/256);
  k_gemm1 <<<gG, 256, 0, stream>>>(w, z1, z2, embw, embz1, embz2, W0, hx, N);
  k_agg32c<<<gA, 256, 0, stream>>>(hx, dis, rs, csr, b0, h1c, N);
  k_gemm32<<<gG, 256, 0, stream>>>(h1c, W1, hx, N);
  k_agg32c<<<gA, 256, 0, stream>>>(hx, dis, rs, csr, b1, h2c, N);
  k_gemm32<<<gG, 256, 0, stream>>>(h2c, W2, hx, N);
  k_agg32c<<<gA, 256, 0, stream>>>(hx, dis, rs, csr, b2, h3c, N);
  k_gemmv <<<(N+255)/256, 256, 0, stream>>>(h3c, W3, hx, N);
  k_agg1  <<<(N+255)/256, 256, 0, stream>>>(hx, dis, rs, csr, b3, h4, N);

  k_head<<<B, 256, 0, stream>>>(h1c, h2c, h3c, h4, c1W, c1b, c2W, c2b,
                                l1W, l1b, l2W, l2b, out, N);
}

// Round 4
// 854.868 us; speedup vs baseline: 2.7719x; 2.7719x over previous
//
#include <hip/hip_runtime.h>
#include <math.h>

#define NPG 100
#define KTOP 60
#define DLAT 97
#define NB 2000         // buckets = graphs
#define NBLK 128        // binning blocks
#define CPB 25000       // edges per binning block = ceil(3.2M/128)

static __device__ __forceinline__ float dot4(float4 a, float4 b){
  return a.x*b.x + a.y*b.y + a.z*b.z + a.w*b.w;
}

// ---------------- prep: atomic-free CSR build via per-graph bucketing ----------------
__global__ __launch_bounds__(256) void k_hist(const int* __restrict__ dst, int* __restrict__ histG, int E){
  __shared__ int h[NB];
  int blk = blockIdx.x, tid = threadIdx.x;
  for(int i=tid;i<NB;i+=256) h[i]=0;
  __syncthreads();
  int e0 = blk*CPB, e1 = min(e0+CPB, E);
  for(int e=e0+tid; e<e1; e+=256) atomicAdd(&h[dst[e]/NPG], 1);
  __syncthreads();
  for(int i=tid;i<NB;i+=256) histG[blk*NB+i] = h[i];
}

// block per bucket: exclusive scan of histG[:,b] over blocks
__global__ __launch_bounds__(NBLK) void k_colscan(const int* __restrict__ histG,
    int* __restrict__ prefT, int* __restrict__ total){
  __shared__ int s[NBLK];
  int b = blockIdx.x, t = threadIdx.x;
  int v = histG[t*NB + b];
  s[t] = v;
  __syncthreads();
  for(int off=1; off<NBLK; off<<=1){
    int u = (t >= off) ? s[t-off] : 0;
    __syncthreads();
    s[t] += u;
    __syncthreads();
  }
  prefT[b*NBLK + t] = s[t] - v;
  if(t == NBLK-1) total[b] = s[t];
}

__global__ __launch_bounds__(1024) void k_bscan(const int* __restrict__ total, int* __restrict__ bbase){
  __shared__ int s[1024];
  int t = threadIdx.x;
  int i0 = 2*t, i1 = 2*t+1;
  int x0 = (i0 < NB) ? total[i0] : 0;
  int x1 = (i1 < NB) ? total[i1] : 0;
  int ps = x0 + x1;
  s[t] = ps;
  __syncthreads();
  for(int off=1; off<1024; off<<=1){
    int u = (t >= off) ? s[t-off] : 0;
    __syncthreads();
    s[t] += u;
    __syncthreads();
  }
  int excl = s[t] - ps;
  if(i0 < NB) bbase[i0] = excl;
  if(i1 < NB) bbase[i1] = excl + x0;
  if(t == 1023) bbase[NB] = s[1023];
}

// packed edge: x = src | (dst%NPG)<<18  (src<2^18, dstmod<2^7), y = bits of ew
__global__ __launch_bounds__(256) void k_scatter(const int* __restrict__ src, const int* __restrict__ dst,
    const float* __restrict__ ew, const int* __restrict__ prefT, const int* __restrict__ bbase,
    int2* __restrict__ ebuf, int E){
  __shared__ int cur[NB];
  int blk = blockIdx.x, tid = threadIdx.x;
  for(int i=tid;i<NB;i+=256) cur[i] = prefT[i*NBLK + blk] + bbase[i];
  __syncthreads();
  int e0 = blk*CPB, e1 = min(e0+CPB, E);
  for(int e=e0+tid; e<e1; e+=256){
    int d = dst[e];
    int b = d/NPG;
    int dmod = d - b*NPG;
    int pos = atomicAdd(&cur[b], 1);          // LDS atomic
    ebuf[pos] = make_int2(src[e] | (dmod<<18), __float_as_int(ew[e]));
  }
}

// block per graph: degree -> dis, row starts, scatter to CSR (int2{src, ew})
__global__ __launch_bounds__(256) void k_bucket(const int2* __restrict__ ebuf, const int* __restrict__ bbase,
    float* __restrict__ dis, int* __restrict__ rs, int2* __restrict__ csr, int N){
  __shared__ float degw[NPG];
  __shared__ int cnt[NPG];
  __shared__ int cur[NPG];
  __shared__ int sc[128];
  int g = blockIdx.x, tid = threadIdx.x;
  int g0 = g*NPG;
  if(tid < NPG){ degw[tid] = 0.f; cnt[tid] = 0; }
  __syncthreads();
  int e0 = bbase[g], e1 = bbase[g+1];
  for(int e=e0+tid; e<e1; e+=256){
    int2 t = ebuf[e];
    int ld = ((unsigned)t.x)>>18;
    atomicAdd(&cnt[ld], 1);
    atomicAdd(&degw[ld], __int_as_float(t.y));
  }
  __syncthreads();
  if(tid < NPG) dis[g0+tid] = rsqrtf(degw[tid] + 1.0f);
  if(tid < 128) sc[tid] = (tid < NPG) ? cnt[tid] : 0;
  __syncthreads();
  for(int off=1; off<128; off<<=1){
    int u = 0;
    if(tid < 128 && tid >= off) u = sc[tid-off];
    __syncthreads();
    if(tid < 128) sc[tid] += u;
    __syncthreads();
  }
  if(tid < NPG){
    int st = e0 + sc[tid] - cnt[tid];
    cur[tid] = st;
    rs[g0+tid] = st;
  }
  if(g == NB-1 && tid == 0) rs[N] = e1;
  __syncthreads();
  for(int e=e0+tid; e<e1; e+=256){
    int2 t = ebuf[e];
    int ld = ((unsigned)t.x)>>18;
    int pos = atomicAdd(&cur[ld], 1);
    csr[pos] = make_int2(t.x & 0x3FFFF, t.y);
  }
}

// ---------------- GEMMs (row-major out, pre-scaled by dis[n]) ----------------
__global__ __launch_bounds__(256) void k_gemm1(const int* __restrict__ wI, const int* __restrict__ z1I,
   const int* __restrict__ z2I,
   const float* __restrict__ embw, const float* __restrict__ embz1, const float* __restrict__ embz2,
   const float* __restrict__ W0, const float* __restrict__ dis, float* __restrict__ gx, int N){
  __shared__ __align__(16) float X[128][97];   // stride 97: conflict-free in compute loop
  __shared__ __align__(16) float Ws[96*32];
  __shared__ int iw[128], i1[128], i2[128];
  int tid = threadIdx.x;
  int g0 = blockIdx.x*128;
  for(int i=tid;i<768;i+=256) ((float4*)Ws)[i] = ((const float4*)W0)[i];
  if(tid < 128){
    int gn = g0 + tid;
    bool ok = gn < N;
    iw[tid] = ok ? wI[gn]  : 0;
    i1[tid] = ok ? z1I[gn] : 0;
    i2[tid] = ok ? z2I[gn] : 0;
  }
  __syncthreads();
  for(int r=0;r<48;r++){
    int flat = r*256 + tid;
    int n = flat/96, c = flat - n*96;
    int gn = g0 + n;
    float val = 0.f;
    if(gn < N){
      if(c < 32)      val = embw [iw[n]*32 + c];
      else if(c < 64) val = embz1[i1[n]*32 + (c-32)];
      else            val = embz2[i2[n]*32 + (c-64)];
    }
    X[n][c] = val;
  }
  __syncthreads();
  int ng = tid>>3, chg = tid&7;
  float4 acc[4];
  #pragma unroll
  for(int j=0;j<4;j++) acc[j] = make_float4(0.f,0.f,0.f,0.f);
  #pragma unroll 4
  for(int i=0;i<96;i++){
    float4 wv = *(const float4*)&Ws[i*32 + chg*4];
    #pragma unroll
    for(int j=0;j<4;j++){
      float xv = X[ng*4+j][i];
      acc[j].x += xv*wv.x; acc[j].y += xv*wv.y; acc[j].z += xv*wv.z; acc[j].w += xv*wv.w;
    }
  }
  #pragma unroll
  for(int j=0;j<4;j++){
    int gn = g0 + ng*4 + j;
    if(gn < N){
      float dv = dis[gn];
      acc[j].x *= dv; acc[j].y *= dv; acc[j].z *= dv; acc[j].w *= dv;
      *(float4*)&gx[(size_t)gn*32 + chg*4] = acc[j];
    }
  }
}

__global__ __launch_bounds__(256) void k_gemm32(const float* __restrict__ xin, const float* __restrict__ W,
    const float* __restrict__ dis, float* __restrict__ gx, int N){
  __shared__ __align__(16) float X[128][33];
  __shared__ __align__(16) float Ws[32*32];
  int tid = threadIdx.x;
  int g0 = blockIdx.x*128;
  ((float4*)Ws)[tid] = ((const float4*)W)[tid];
  for(int r=0;r<4;r++){
    int f = r*256 + tid;               // float4 id: 128 nodes x 8
    int n = f>>3, c4 = f&7;
    int gn = g0 + n;
    float4 v = (gn < N) ? ((const float4*)(xin + (size_t)gn*32))[c4] : make_float4(0,0,0,0);
    float* xr = &X[n][c4*4];
    xr[0]=v.x; xr[1]=v.y; xr[2]=v.z; xr[3]=v.w;
  }
  __syncthreads();
  int ng = tid>>3, chg = tid&7;
  float4 acc[4];
  #pragma unroll
  for(int j=0;j<4;j++) acc[j] = make_float4(0.f,0.f,0.f,0.f);
  #pragma unroll 4
  for(int i=0;i<32;i++){
    float4 wv = *(const float4*)&Ws[i*32 + chg*4];
    #pragma unroll
    for(int j=0;j<4;j++){
      float xv = X[ng*4+j][i];
      acc[j].x += xv*wv.x; acc[j].y += xv*wv.y; acc[j].z += xv*wv.z; acc[j].w += xv*wv.w;
    }
  }
  #pragma unroll
  for(int j=0;j<4;j++){
    int gn = g0 + ng*4 + j;
    if(gn < N){
      float dv = dis[gn];
      acc[j].x *= dv; acc[j].y *= dv; acc[j].z *= dv; acc[j].w *= dv;
      *(float4*)&gx[(size_t)gn*32 + chg*4] = acc[j];
    }
  }
}

__global__ __launch_bounds__(256) void k_gemmv(const float* __restrict__ xin, const float* __restrict__ W3,
    const float* __restrict__ dis, float* __restrict__ gv, int N){
  __shared__ float X[256][33];
  __shared__ float Ws[32];
  int tid = threadIdx.x;
  int g0 = blockIdx.x*256;
  if(tid < 32) Ws[tid] = W3[tid];
  for(int r=0;r<8;r++){
    int f = r*256 + tid;               // float4 id: 256 nodes x 8
    int n = f>>3, c4 = f&7;
    int gn = g0 + n;
    float4 v = (gn < N) ? ((const float4*)(xin + (size_t)gn*32))[c4] : make_float4(0,0,0,0);
    float* xr = &X[n][c4*4];
    xr[0]=v.x; xr[1]=v.y; xr[2]=v.z; xr[3]=v.w;
  }
  __syncthreads();
  float acc = 0.f;
  #pragma unroll
  for(int i=0;i<32;i++) acc += X[tid][i]*Ws[i];
  int gn = g0 + tid;
  if(gn < N) gv[gn] = acc*dis[gn];
}

// ---------------- aggregation: wave per dst node, 8 edges x 8 ch-groups ----------------
__global__ __launch_bounds__(256) void k_agg32(const float* __restrict__ g,   // dis-scaled [N][32]
   const float* __restrict__ dis, const int* __restrict__ rs, const int2* __restrict__ csr,
   const float* __restrict__ bias, float* __restrict__ hout, int N){
  int wave = threadIdx.x >> 6;
  int lane = threadIdx.x & 63;
  int es = lane >> 3;          // edge slot 0..7
  int cg = lane & 7;           // channel group (4 ch)
  int n = blockIdx.x*4 + wave;
  if(n >= N) return;
  int e0 = rs[n], e1 = rs[n+1];
  int deg = e1 - e0;
  int full = deg >> 3, rem = deg & 7;
  float4 acc = make_float4(0.f,0.f,0.f,0.f);
  int idx = e0 + es;
  for(int it=0; it<full; ++it){
    int2 p = csr[idx];
    float w = __int_as_float(p.y);
    float4 v = ((const float4*)(g + (size_t)p.x*32))[cg];
    acc.x += w*v.x; acc.y += w*v.y; acc.z += w*v.z; acc.w += w*v.w;
    idx += 8;
  }
  if(es < rem){
    int2 p = csr[idx];
    float w = __int_as_float(p.y);
    float4 v = ((const float4*)(g + (size_t)p.x*32))[cg];
    acc.x += w*v.x; acc.y += w*v.y; acc.z += w*v.z; acc.w += w*v.w;
  }
  #pragma unroll
  for(int off=8; off<64; off<<=1){
    acc.x += __shfl_xor(acc.x, off);
    acc.y += __shfl_xor(acc.y, off);
    acc.z += __shfl_xor(acc.z, off);
    acc.w += __shfl_xor(acc.w, off);
  }
  float4 self = ((const float4*)(g + (size_t)n*32))[cg];
  float dn = dis[n];
  float4 bv = ((const float4*)bias)[cg];
  if(es == 0){
    float4 o;
    o.x = tanhf(dn*(acc.x + self.x) + bv.x);
    o.y = tanhf(dn*(acc.y + self.y) + bv.y);
    o.z = tanhf(dn*(acc.z + self.z) + bv.z);
    o.w = tanhf(dn*(acc.w + self.w) + bv.w);
    ((float4*)(hout + (size_t)n*32))[cg] = o;
  }
}

__global__ void k_agg1(const float* __restrict__ gv, const float* __restrict__ dis,
   const int* __restrict__ rs, const int2* __restrict__ csr,
   const float* __restrict__ b3, float* __restrict__ h4, int N){
  int n = blockIdx.x*256 + threadIdx.x;
  if(n >= N) return;
  float acc = gv[n];           // self (already dis-scaled)
  int e0 = rs[n], e1 = rs[n+1];
  for(int e=e0;e<e1;e++){
    int2 p = csr[e];
    acc += __int_as_float(p.y)*gv[p.x];
  }
  h4[n] = tanhf(dis[n]*acc + b3[0]);
}

// ---------------- fused head ----------------
__global__ __launch_bounds__(256) void k_head(const float* __restrict__ h1,const float* __restrict__ h2,
  const float* __restrict__ h3,const float* __restrict__ h4,
  const float* __restrict__ c1W,const float* __restrict__ c1b,
  const float* __restrict__ c2W,const float* __restrict__ c2b,
  const float* __restrict__ l1W,const float* __restrict__ l1b,
  const float* __restrict__ l2W,const float* __restrict__ l2b,
  float* __restrict__ out, int N){
  __shared__ float v[100];
  __shared__ int ord[KTOP];
  __shared__ __align__(16) float xk[KTOP][100];
  __shared__ __align__(16) float c1Ws[16*100];
  __shared__ __align__(16) float t1[16][60];
  __shared__ __align__(16) float t2[16][32];
  __shared__ __align__(16) float c2Ws[32*16*5];
  __shared__ __align__(16) float flat[832];
  __shared__ __align__(16) float o1s[2][128];
  int b = blockIdx.x, tid = threadIdx.x;
  int g0 = b*NPG;
  for(int i=tid;i<16*97;i+=256){ int o=i/97, d=i-o*97; c1Ws[o*100+d]=c1W[i]; }
  for(int i=tid;i<2560;i+=256) c2Ws[i]=c2W[i];
  if(tid < 100) v[tid] = h4[g0+tid];
  __syncthreads();
  if(tid < 100){
    float vi = v[tid];
    int rank = 0;
    for(int j=0;j<100;j++){
      float vj = v[j];
      rank += (vj > vi) || (vj == vi && j < tid);
    }
    if(rank < KTOP) ord[rank] = tid;
  }
  __syncthreads();
  for(int idx=tid; idx<KTOP*DLAT; idx+=256){
    int k = idx/DLAT, d = idx - k*DLAT;
    int n = g0 + ord[k];
    float val;
    if(d < 96){
      const float* hsrc = (d<32) ? h1 : (d<64) ? h2 : h3;
      val = hsrc[(size_t)n*32 + (d&31)];
    } else val = h4[n];
    xk[k][d] = val;
  }
  __syncthreads();
  if(tid < 120){
    int og = tid/15, kg = tid - og*15;
    float a0[4] = {0,0,0,0}, a1[4] = {0,0,0,0};
    for(int d=0; d<96; d+=4){
      float4 w0 = *(const float4*)&c1Ws[og*100 + d];
      float4 w1 = *(const float4*)&c1Ws[(og+8)*100 + d];
      #pragma unroll
      for(int j=0;j<4;j++){
        float4 xv = *(const float4*)&xk[kg + 15*j][d];
        a0[j] += dot4(xv, w0);
        a1[j] += dot4(xv, w1);
      }
    }
    {
      float w0 = c1Ws[og*100 + 96], w1 = c1Ws[(og+8)*100 + 96];
      #pragma unroll
      for(int j=0;j<4;j++){
        float xv = xk[kg + 15*j][96];
        a0[j] += xv*w0;
        a1[j] += xv*w1;
      }
    }
    float b0v = c1b[og], b1v = c1b[og+8];
    #pragma unroll
    for(int j=0;j<4;j++){
      t1[og  ][kg + 15*j] = fmaxf(a0[j] + b0v, 0.f);
      t1[og+8][kg + 15*j] = fmaxf(a1[j] + b1v, 0.f);
    }
  }
  __syncthreads();
  for(int idx=tid; idx<480; idx+=256){
    int o = idx/30, jj = idx - o*30;
    t2[o][jj] = fmaxf(t1[o][2*jj], t1[o][2*jj+1]);
  }
  __syncthreads();
  if(tid < 224){
    int oc = tid/7, pg = tid - oc*7;
    int p0 = pg*4;
    float acc[4] = {0,0,0,0};
    for(int ic=0; ic<16; ic++){
      float4 A  = *(const float4*)&t2[ic][p0];
      float4 Bv = *(const float4*)&t2[ic][p0+4];
      float e[8] = {A.x,A.y,A.z,A.w,Bv.x,Bv.y,Bv.z,Bv.w};
      const float* wr = &c2Ws[(oc*16 + ic)*5];
      #pragma unroll
      for(int q=0;q<4;q++){
        #pragma unroll
        for(int r=0;r<5;r++) acc[q] += e[q+r]*wr[r];
      }
    }
    float bb = c2b[oc];
    #pragma unroll
    for(int q=0;q<4;q++){
      int p = p0 + q;
      if(p < 26) flat[oc*26 + p] = fmaxf(acc[q] + bb, 0.f);
    }
  }
  __syncthreads();
  {
    int half = tid>>7, j = tid&127;
    int i0 = half*416;
    float s = 0.f;
    #pragma unroll 4
    for(int i=0;i<416;i++){
      s += flat[i0+i] * l1W[(size_t)(i0+i)*128 + j];
    }
    o1s[half][j] = s;
  }
  __syncthreads();
  if(tid < 128){
    float r = o1s[0][tid] + o1s[1][tid] + l1b[tid];
    o1s[0][tid] = fmaxf(r, 0.f);
  }
  __syncthreads();
  float* red = (float*)t1;
  if(tid < 128) red[tid] = o1s[0][tid]*l2W[tid];
  __syncthreads();
  if(tid < 64){
    float val = red[tid] + red[tid+64];
    #pragma unroll
    for(int off=32; off>0; off>>=1) val += __shfl_down(val, off);
    if(tid == 0) out[b] = val + l2b[0];
  }
}

// ---------------- launch ----------------
extern "C" void kernel_launch(void* const* d_in, const int* in_sizes, int n_in,
                              void* d_out, int out_size, void* d_ws, size_t ws_size,
                              hipStream_t stream){
  (void)n_in; (void)out_size; (void)ws_size;
  const int*   z1    = (const int*)  d_in[0];
  const int*   z2    = (const int*)  d_in[1];
  const int*   w     = (const int*)  d_in[2];
  const int*   eidx  = (const int*)  d_in[3];
  const float* ew    = (const float*)d_in[5];
  const float* embw  = (const float*)d_in[6];
  const float* embz1 = (const float*)d_in[7];
  const float* embz2 = (const float*)d_in[8];
  const float* W0    = (const float*)d_in[9];
  const float* b0    = (const float*)d_in[10];
  const float* W1    = (const float*)d_in[11];
  const float* b1    = (const float*)d_in[12];
  const float* W2    = (const float*)d_in[13];
  const float* b2    = (const float*)d_in[14];
  const float* W3    = (const float*)d_in[15];
  const float* b3    = (const float*)d_in[16];
  const float* c1W   = (const float*)d_in[17];
  const float* c1b   = (const float*)d_in[18];
  const float* c2W   = (const float*)d_in[19];
  const float* c2b   = (const float*)d_in[20];
  const float* l1W   = (const float*)d_in[21];
  const float* l1b   = (const float*)d_in[22];
  const float* l2W   = (const float*)d_in[23];
  const float* l2b   = (const float*)d_in[24];
  float* out = (float*)d_out;

  int N = in_sizes[0];
  int E = in_sizes[3]/2;
  int B = N/NPG;
  const int* src = eidx;
  const int* dst = eidx + E;

  char* p = (char*)d_ws;
  auto alloc = [&](size_t bytes)->char*{
    char* r = p;
    p += (bytes + 255) & ~(size_t)255;
    return r;
  };
  float* h1    = (float*)alloc((size_t)N*32*4);
  float* h2    = (float*)alloc((size_t)N*32*4);
  float* h3    = (float*)alloc((size_t)N*32*4);
  float* h4    = (float*)alloc((size_t)N*4);
  float* gx    = (float*)alloc((size_t)N*32*4);
  float* dis   = (float*)alloc((size_t)N*4);
  int*   rs    = (int*)  alloc((size_t)(N+1)*4);
  int*   histG = (int*)  alloc((size_t)NBLK*NB*4);
  int*   prefT = (int*)  alloc((size_t)NB*NBLK*4);
  int*   total = (int*)  alloc((size_t)NB*4);
  int*   bbase = (int*)  alloc((size_t)(NB+1)*4);
  int2*  csr   = (int2*) alloc((size_t)E*8);
  int2*  ebuf  = (int2*)h1;    // alias: 25.6MB fits exactly in h1; dead before h1 written

  k_hist   <<<NBLK, 256, 0, stream>>>(dst, histG, E);
  k_colscan<<<NB,  NBLK, 0, stream>>>(histG, prefT, total);
  k_bscan  <<<1,   1024, 0, stream>>>(total, bbase);
  k_scatter<<<NBLK, 256, 0, stream>>>(src, dst, ew, prefT, bbase, ebuf, E);
  k_bucket <<<B,    256, 0, stream>>>(ebuf, bbase, dis, rs, csr, N);

  int gG = (N+127)/128;
  int gA = (N+3)/4;
  k_gemm1 <<<gG, 256, 0, stream>>>(w, z1, z2, embw, embz1, embz2, W0, dis, gx, N);
  k_agg32 <<<gA, 256, 0, stream>>>(gx, dis, rs, csr, b0, h1, N);
  k_gemm32<<<gG, 256, 0, stream>>>(h1, W1, dis, gx, N);
  k_agg32 <<<gA, 256, 0, stream>>>(gx, dis, rs, csr, b1, h2, N);
  k_gemm32<<<gG, 256, 0, stream>>>(h2, W2, dis, gx, N);
  k_agg32 <<<gA, 256, 0, stream>>>(gx, dis, rs, csr, b2, h3, N);
  k_gemmv <<<(N+255)/256, 256, 0, stream>>>(h3, W3, dis, gx, N);
  k_agg1  <<<(N+255)/256, 256, 0, stream>>>(gx, dis, rs, csr, b3, h4, N);

  k_head<<<B, 256, 0, stream>>>(h1, h2, h3, h4, c1W, c1b, c2W, c2b,
                                l1W, l1b, l2W, l2b, out, N);
}

// Round 5
// 809.843 us; speedup vs baseline: 2.9260x; 1.0556x over previous
//
#include <hip/hip_runtime.h>
#include <math.h>

#define NPG 100
#define KTOP 60
#define DLAT 97
#define NB 2000         // buckets = graphs
#define NBLK 128        // binning blocks
#define CPB 25000       // edges per binning block = ceil(3.2M/128)

static __device__ __forceinline__ float dot4(float4 a, float4 b){
  return a.x*b.x + a.y*b.y + a.z*b.z + a.w*b.w;
}

// ---------------- prep: atomic-free CSR build via per-graph bucketing ----------------
__global__ __launch_bounds__(256) void k_hist(const int* __restrict__ dst, int* __restrict__ histG, int E){
  __shared__ int h[NB];
  int blk = blockIdx.x, tid = threadIdx.x;
  for(int i=tid;i<NB;i+=256) h[i]=0;
  __syncthreads();
  int e0 = blk*CPB, e1 = min(e0+CPB, E);
  for(int e=e0+tid; e<e1; e+=256) atomicAdd(&h[dst[e]/NPG], 1);
  __syncthreads();
  for(int i=tid;i<NB;i+=256) histG[blk*NB+i] = h[i];
}

__global__ __launch_bounds__(NBLK) void k_colscan(const int* __restrict__ histG,
    int* __restrict__ prefT, int* __restrict__ total){
  __shared__ int s[NBLK];
  int b = blockIdx.x, t = threadIdx.x;
  int v = histG[t*NB + b];
  s[t] = v;
  __syncthreads();
  for(int off=1; off<NBLK; off<<=1){
    int u = (t >= off) ? s[t-off] : 0;
    __syncthreads();
    s[t] += u;
    __syncthreads();
  }
  prefT[b*NBLK + t] = s[t] - v;
  if(t == NBLK-1) total[b] = s[t];
}

__global__ __launch_bounds__(1024) void k_bscan(const int* __restrict__ total, int* __restrict__ bbase){
  __shared__ int s[1024];
  int t = threadIdx.x;
  int i0 = 2*t, i1 = 2*t+1;
  int x0 = (i0 < NB) ? total[i0] : 0;
  int x1 = (i1 < NB) ? total[i1] : 0;
  int ps = x0 + x1;
  s[t] = ps;
  __syncthreads();
  for(int off=1; off<1024; off<<=1){
    int u = (t >= off) ? s[t-off] : 0;
    __syncthreads();
    s[t] += u;
    __syncthreads();
  }
  int excl = s[t] - ps;
  if(i0 < NB) bbase[i0] = excl;
  if(i1 < NB) bbase[i1] = excl + x0;
  if(t == 1023) bbase[NB] = s[1023];
}

// packed edge: x = src | (dst%NPG)<<18, y = bits of ew
__global__ __launch_bounds__(256) void k_scatter(const int* __restrict__ src, const int* __restrict__ dst,
    const float* __restrict__ ew, const int* __restrict__ prefT, const int* __restrict__ bbase,
    int2* __restrict__ ebuf, int E){
  __shared__ int cur[NB];
  int blk = blockIdx.x, tid = threadIdx.x;
  for(int i=tid;i<NB;i+=256) cur[i] = prefT[i*NBLK + blk] + bbase[i];
  __syncthreads();
  int e0 = blk*CPB, e1 = min(e0+CPB, E);
  for(int e=e0+tid; e<e1; e+=256){
    int d = dst[e];
    int b = d/NPG;
    int dmod = d - b*NPG;
    int pos = atomicAdd(&cur[b], 1);          // LDS atomic
    ebuf[pos] = make_int2(src[e] | (dmod<<18), __float_as_int(ew[e]));
  }
}

__global__ __launch_bounds__(256) void k_bucket(const int2* __restrict__ ebuf, const int* __restrict__ bbase,
    float* __restrict__ dis, int* __restrict__ rs, int2* __restrict__ csr, int N){
  __shared__ float degw[NPG];
  __shared__ int cnt[NPG];
  __shared__ int cur[NPG];
  __shared__ int sc[128];
  int g = blockIdx.x, tid = threadIdx.x;
  int g0 = g*NPG;
  if(tid < NPG){ degw[tid] = 0.f; cnt[tid] = 0; }
  __syncthreads();
  int e0 = bbase[g], e1 = bbase[g+1];
  for(int e=e0+tid; e<e1; e+=256){
    int2 t = ebuf[e];
    int ld = ((unsigned)t.x)>>18;
    atomicAdd(&cnt[ld], 1);
    atomicAdd(&degw[ld], __int_as_float(t.y));
  }
  __syncthreads();
  if(tid < NPG) dis[g0+tid] = rsqrtf(degw[tid] + 1.0f);
  if(tid < 128) sc[tid] = (tid < NPG) ? cnt[tid] : 0;
  __syncthreads();
  for(int off=1; off<128; off<<=1){
    int u = 0;
    if(tid < 128 && tid >= off) u = sc[tid-off];
    __syncthreads();
    if(tid < 128) sc[tid] += u;
    __syncthreads();
  }
  if(tid < NPG){
    int st = e0 + sc[tid] - cnt[tid];
    cur[tid] = st;
    rs[g0+tid] = st;
  }
  if(g == NB-1 && tid == 0) rs[N] = e1;
  __syncthreads();
  for(int e=e0+tid; e<e1; e+=256){
    int2 t = ebuf[e];
    int ld = ((unsigned)t.x)>>18;
    int pos = atomicAdd(&cur[ld], 1);
    csr[pos] = make_int2(t.x & 0x3FFFF, t.y);
  }
}

// ---------------- GEMMs (row-major out, pre-scaled by dis[n]) ----------------
__global__ __launch_bounds__(256) void k_gemm1(const int* __restrict__ wI, const int* __restrict__ z1I,
   const int* __restrict__ z2I,
   const float* __restrict__ embw, const float* __restrict__ embz1, const float* __restrict__ embz2,
   const float* __restrict__ W0, const float* __restrict__ dis, float* __restrict__ gx, int N){
  __shared__ __align__(16) float X[128][97];
  __shared__ __align__(16) float Ws[96*32];
  __shared__ int iw[128], i1[128], i2[128];
  int tid = threadIdx.x;
  int g0 = blockIdx.x*128;
  for(int i=tid;i<768;i+=256) ((float4*)Ws)[i] = ((const float4*)W0)[i];
  if(tid < 128){
    int gn = g0 + tid;
    bool ok = gn < N;
    iw[tid] = ok ? wI[gn]  : 0;
    i1[tid] = ok ? z1I[gn] : 0;
    i2[tid] = ok ? z2I[gn] : 0;
  }
  __syncthreads();
  for(int r=0;r<48;r++){
    int flat = r*256 + tid;
    int n = flat/96, c = flat - n*96;
    int gn = g0 + n;
    float val = 0.f;
    if(gn < N){
      if(c < 32)      val = embw [iw[n]*32 + c];
      else if(c < 64) val = embz1[i1[n]*32 + (c-32)];
      else            val = embz2[i2[n]*32 + (c-64)];
    }
    X[n][c] = val;
  }
  __syncthreads();
  int ng = tid>>3, chg = tid&7;
  float4 acc[4];
  #pragma unroll
  for(int j=0;j<4;j++) acc[j] = make_float4(0.f,0.f,0.f,0.f);
  #pragma unroll 4
  for(int i=0;i<96;i++){
    float4 wv = *(const float4*)&Ws[i*32 + chg*4];
    #pragma unroll
    for(int j=0;j<4;j++){
      float xv = X[ng*4+j][i];
      acc[j].x += xv*wv.x; acc[j].y += xv*wv.y; acc[j].z += xv*wv.z; acc[j].w += xv*wv.w;
    }
  }
  #pragma unroll
  for(int j=0;j<4;j++){
    int gn = g0 + ng*4 + j;
    if(gn < N){
      float dv = dis[gn];
      acc[j].x *= dv; acc[j].y *= dv; acc[j].z *= dv; acc[j].w *= dv;
      *(float4*)&gx[(size_t)gn*32 + chg*4] = acc[j];
    }
  }
}

__global__ __launch_bounds__(256) void k_gemm32(const float* __restrict__ xin, const float* __restrict__ W,
    const float* __restrict__ dis, float* __restrict__ gx, int N){
  __shared__ __align__(16) float X[128][33];
  __shared__ __align__(16) float Ws[32*32];
  int tid = threadIdx.x;
  int g0 = blockIdx.x*128;
  ((float4*)Ws)[tid] = ((const float4*)W)[tid];
  for(int r=0;r<4;r++){
    int f = r*256 + tid;
    int n = f>>3, c4 = f&7;
    int gn = g0 + n;
    float4 v = (gn < N) ? ((const float4*)(xin + (size_t)gn*32))[c4] : make_float4(0,0,0,0);
    float* xr = &X[n][c4*4];
    xr[0]=v.x; xr[1]=v.y; xr[2]=v.z; xr[3]=v.w;
  }
  __syncthreads();
  int ng = tid>>3, chg = tid&7;
  float4 acc[4];
  #pragma unroll
  for(int j=0;j<4;j++) acc[j] = make_float4(0.f,0.f,0.f,0.f);
  #pragma unroll 4
  for(int i=0;i<32;i++){
    float4 wv = *(const float4*)&Ws[i*32 + chg*4];
    #pragma unroll
    for(int j=0;j<4;j++){
      float xv = X[ng*4+j][i];
      acc[j].x += xv*wv.x; acc[j].y += xv*wv.y; acc[j].z += xv*wv.z; acc[j].w += xv*wv.w;
    }
  }
  #pragma unroll
  for(int j=0;j<4;j++){
    int gn = g0 + ng*4 + j;
    if(gn < N){
      float dv = dis[gn];
      acc[j].x *= dv; acc[j].y *= dv; acc[j].z *= dv; acc[j].w *= dv;
      *(float4*)&gx[(size_t)gn*32 + chg*4] = acc[j];
    }
  }
}

__global__ __launch_bounds__(256) void k_gemmv(const float* __restrict__ xin, const float* __restrict__ W3,
    const float* __restrict__ dis, float* __restrict__ gv, int N){
  __shared__ float X[256][33];
  __shared__ float Ws[32];
  int tid = threadIdx.x;
  int g0 = blockIdx.x*256;
  if(tid < 32) Ws[tid] = W3[tid];
  for(int r=0;r<8;r++){
    int f = r*256 + tid;
    int n = f>>3, c4 = f&7;
    int gn = g0 + n;
    float4 v = (gn < N) ? ((const float4*)(xin + (size_t)gn*32))[c4] : make_float4(0,0,0,0);
    float* xr = &X[n][c4*4];
    xr[0]=v.x; xr[1]=v.y; xr[2]=v.z; xr[3]=v.w;
  }
  __syncthreads();
  float acc = 0.f;
  #pragma unroll
  for(int i=0;i<32;i++) acc += X[tid][i]*Ws[i];
  int gn = g0 + tid;
  if(gn < N) gv[gn] = acc*dis[gn];
}

// ---------------- aggregation: wave per dst node, 8 edges x 8 ch-groups ----------------
__global__ __launch_bounds__(256) void k_agg32(const float* __restrict__ g,
   const float* __restrict__ dis, const int* __restrict__ rs, const int2* __restrict__ csr,
   const float* __restrict__ bias, float* __restrict__ hout, int N){
  int wave = threadIdx.x >> 6;
  int lane = threadIdx.x & 63;
  int es = lane >> 3;
  int cg = lane & 7;
  int n = blockIdx.x*4 + wave;
  if(n >= N) return;
  int e0 = rs[n], e1 = rs[n+1];
  int deg = e1 - e0;
  int full = deg >> 3, rem = deg & 7;
  float4 acc = make_float4(0.f,0.f,0.f,0.f);
  int idx = e0 + es;
  for(int it=0; it<full; ++it){
    int2 p = csr[idx];
    float w = __int_as_float(p.y);
    float4 v = ((const float4*)(g + (size_t)p.x*32))[cg];
    acc.x += w*v.x; acc.y += w*v.y; acc.z += w*v.z; acc.w += w*v.w;
    idx += 8;
  }
  if(es < rem){
    int2 p = csr[idx];
    float w = __int_as_float(p.y);
    float4 v = ((const float4*)(g + (size_t)p.x*32))[cg];
    acc.x += w*v.x; acc.y += w*v.y; acc.z += w*v.z; acc.w += w*v.w;
  }
  #pragma unroll
  for(int off=8; off<64; off<<=1){
    acc.x += __shfl_xor(acc.x, off);
    acc.y += __shfl_xor(acc.y, off);
    acc.z += __shfl_xor(acc.z, off);
    acc.w += __shfl_xor(acc.w, off);
  }
  float4 self = ((const float4*)(g + (size_t)n*32))[cg];
  float dn = dis[n];
  float4 bv = ((const float4*)bias)[cg];
  if(es == 0){
    float4 o;
    o.x = tanhf(dn*(acc.x + self.x) + bv.x);
    o.y = tanhf(dn*(acc.y + self.y) + bv.y);
    o.z = tanhf(dn*(acc.z + self.z) + bv.z);
    o.w = tanhf(dn*(acc.w + self.w) + bv.w);
    ((float4*)(hout + (size_t)n*32))[cg] = o;
  }
}

__global__ void k_agg1(const float* __restrict__ gv, const float* __restrict__ dis,
   const int* __restrict__ rs, const int2* __restrict__ csr,
   const float* __restrict__ b3, float* __restrict__ h4, int N){
  int n = blockIdx.x*256 + threadIdx.x;
  if(n >= N) return;
  float acc = gv[n];
  int e0 = rs[n], e1 = rs[n+1];
  for(int e=e0;e<e1;e++){
    int2 p = csr[e];
    acc += __int_as_float(p.y)*gv[p.x];
  }
  h4[n] = tanhf(dis[n]*acc + b3[0]);
}

// ---------------- kA: per-graph sort + gather + conv1 + maxpool -> t2G[B][16][30] ----------------
__global__ __launch_bounds__(256) void k_sortpool(const float* __restrict__ h1,const float* __restrict__ h2,
  const float* __restrict__ h3,const float* __restrict__ h4,
  const float* __restrict__ c1W,const float* __restrict__ c1b,
  float* __restrict__ t2G, int N){
  __shared__ float v[128];
  __shared__ int ord[KTOP];
  __shared__ __align__(16) float xk[KTOP][100];
  __shared__ __align__(16) float c1Ws[16*100];
  __shared__ __align__(16) float t2s[480];
  int b = blockIdx.x, tid = threadIdx.x;
  int g0 = b*NPG;
  for(int i=tid;i<16*97;i+=256){ int o=i/97, d=i-o*97; c1Ws[o*100+d]=c1W[i]; }
  if(tid < 100) v[tid] = h4[g0+tid];
  __syncthreads();
  // stable descending rank == argsort(-v) stable
  if(tid < 100){
    float vi = v[tid];
    int rank = 0;
    for(int j=0;j<100;j++){
      float vj = v[j];
      rank += (vj > vi) || (vj == vi && j < tid);
    }
    if(rank < KTOP) ord[rank] = tid;
  }
  __syncthreads();
  // gather top-K rows: x = [h1|h2|h3|h4]
  for(int idx=tid; idx<KTOP*DLAT; idx+=256){
    int k = idx/DLAT, d = idx - k*DLAT;
    int n = g0 + ord[k];
    float val;
    if(d < 96){
      const float* hsrc = (d<32) ? h1 : (d<64) ? h2 : h3;
      val = hsrc[(size_t)n*32 + (d&31)];
    } else val = h4[n];
    xk[k][d] = val;
  }
  __syncthreads();
  // conv1 + relu + maxpool(2,2), all fused in registers
  // thread map: og = tid&7 (o in {og, og+8}), j = tid>>3 (pool slot, j<30)
  {
    int og = tid & 7, j = tid >> 3;
    if(j < 30){
      int k0 = 2*j, k1 = 2*j+1;
      float a00=0.f, a01=0.f, a10=0.f, a11=0.f;  // a[o-half][k-half]
      for(int d=0; d<96; d+=4){
        float4 w0 = *(const float4*)&c1Ws[og*100 + d];
        float4 w1 = *(const float4*)&c1Ws[(og+8)*100 + d];
        float4 x0 = *(const float4*)&xk[k0][d];
        float4 x1 = *(const float4*)&xk[k1][d];
        a00 += dot4(x0, w0); a01 += dot4(x1, w0);
        a10 += dot4(x0, w1); a11 += dot4(x1, w1);
      }
      {
        float w0 = c1Ws[og*100 + 96], w1 = c1Ws[(og+8)*100 + 96];
        float x0 = xk[k0][96], x1 = xk[k1][96];
        a00 += x0*w0; a01 += x1*w0;
        a10 += x0*w1; a11 += x1*w1;
      }
      float b0v = c1b[og], b1v = c1b[og+8];
      float r0 = fmaxf(fmaxf(a00+b0v,0.f), fmaxf(a01+b0v,0.f));
      float r1 = fmaxf(fmaxf(a10+b1v,0.f), fmaxf(a11+b1v,0.f));
      t2s[og*30 + j] = r0;
      t2s[(og+8)*30 + j] = r1;
    }
  }
  __syncthreads();
  if(tid < 120) ((float4*)&t2G[(size_t)b*480])[tid] = ((const float4*)t2s)[tid];
}

// ---------------- kB: conv2 + l1 + l2, 8 graphs per block ----------------
__global__ __launch_bounds__(256) void k_tail(const float* __restrict__ t2G,
  const float* __restrict__ c2W,const float* __restrict__ c2b,
  const float* __restrict__ l1W,const float* __restrict__ l1b,
  const float* __restrict__ l2W,const float* __restrict__ l2b,
  float* __restrict__ out){
  __shared__ __align__(16) float t2s[8*480];       // [g][ic][p] 15.36KB
  __shared__ __align__(16) float c2Ws[2560];       // 10.24KB
  __shared__ __align__(16) float flat[8][832];     // 26.6KB
  __shared__ __align__(16) float o1s[8][128];      // 4KB
  int bG = blockIdx.x, tid = threadIdx.x;
  // stage t2 for 8 graphs + c2W
  for(int i=tid; i<960; i+=256) ((float4*)t2s)[i] = ((const float4*)(t2G + (size_t)bG*8*480))[i];
  for(int i=tid; i<640; i+=256) ((float4*)c2Ws)[i] = ((const float4*)c2W)[i];
  __syncthreads();
  // conv2: thread (g = tid>>5, oc = tid&31); 26 positions, window 5, 16 ic
  {
    int g = tid >> 5, oc = tid & 31;
    float acc[26];
    #pragma unroll
    for(int p=0;p<26;p++) acc[p]=0.f;
    for(int ic=0; ic<16; ic++){
      const float* trow = &t2s[g*480 + ic*30];
      float t[30];
      #pragma unroll
      for(int p=0;p<30;p++) t[p] = trow[p];
      const float* wr = &c2Ws[(oc*16 + ic)*5];
      float w0=wr[0], w1=wr[1], w2=wr[2], w3=wr[3], w4=wr[4];
      #pragma unroll
      for(int p=0;p<26;p++)
        acc[p] += t[p]*w0 + t[p+1]*w1 + t[p+2]*w2 + t[p+3]*w3 + t[p+4]*w4;
    }
    float bb = c2b[oc];
    #pragma unroll
    for(int p=0;p<26;p++) flat[g][oc*26+p] = fmaxf(acc[p]+bb, 0.f);
  }
  __syncthreads();
  // l1: thread (j = tid&127, gq = tid>>7); each handles 4 graphs, l1W loaded once
  {
    int j = tid & 127, gq = tid >> 7;
    float acc0=0.f, acc1=0.f, acc2=0.f, acc3=0.f;
    const float* f0 = flat[gq*4+0];
    const float* f1 = flat[gq*4+1];
    const float* f2 = flat[gq*4+2];
    const float* f3 = flat[gq*4+3];
    for(int i4=0; i4<208; i4++){
      int i = i4*4;
      float w0 = l1W[(size_t)i*128 + j];
      float w1 = l1W[(size_t)(i+1)*128 + j];
      float w2 = l1W[(size_t)(i+2)*128 + j];
      float w3 = l1W[(size_t)(i+3)*128 + j];
      float4 a0 = *(const float4*)&f0[i];
      float4 a1 = *(const float4*)&f1[i];
      float4 a2 = *(const float4*)&f2[i];
      float4 a3 = *(const float4*)&f3[i];
      acc0 += a0.x*w0 + a0.y*w1 + a0.z*w2 + a0.w*w3;
      acc1 += a1.x*w0 + a1.y*w1 + a1.z*w2 + a1.w*w3;
      acc2 += a2.x*w0 + a2.y*w1 + a2.z*w2 + a2.w*w3;
      acc3 += a3.x*w0 + a3.y*w1 + a3.z*w2 + a3.w*w3;
    }
    o1s[gq*4+0][j] = acc0;
    o1s[gq*4+1][j] = acc1;
    o1s[gq*4+2][j] = acc2;
    o1s[gq*4+3][j] = acc3;
  }
  __syncthreads();
  // l2: g = tid>>5, jj = tid&31; each lane sums 4 j-slots, shfl-reduce over 32
  {
    int g = tid >> 5, jj = tid & 31;
    float s = 0.f;
    #pragma unroll
    for(int q=0;q<4;q++){
      int j = jj + 32*q;
      float r = fmaxf(o1s[g][j] + l1b[j], 0.f);
      s += r * l2W[j];
    }
    #pragma unroll
    for(int off=16; off>0; off>>=1) s += __shfl_xor(s, off);
    if(jj == 0) out[bG*8 + g] = s + l2b[0];
  }
}

// ---------------- launch ----------------
extern "C" void kernel_launch(void* const* d_in, const int* in_sizes, int n_in,
                              void* d_out, int out_size, void* d_ws, size_t ws_size,
                              hipStream_t stream){
  (void)n_in; (void)out_size; (void)ws_size;
  const int*   z1    = (const int*)  d_in[0];
  const int*   z2    = (const int*)  d_in[1];
  const int*   w     = (const int*)  d_in[2];
  const int*   eidx  = (const int*)  d_in[3];
  const float* ew    = (const float*)d_in[5];
  const float* embw  = (const float*)d_in[6];
  const float* embz1 = (const float*)d_in[7];
  const float* embz2 = (const float*)d_in[8];
  const float* W0    = (const float*)d_in[9];
  const float* b0    = (const float*)d_in[10];
  const float* W1    = (const float*)d_in[11];
  const float* b1    = (const float*)d_in[12];
  const float* W2    = (const float*)d_in[13];
  const float* b2    = (const float*)d_in[14];
  const float* W3    = (const float*)d_in[15];
  const float* b3    = (const float*)d_in[16];
  const float* c1W   = (const float*)d_in[17];
  const float* c1b   = (const float*)d_in[18];
  const float* c2W   = (const float*)d_in[19];
  const float* c2b   = (const float*)d_in[20];
  const float* l1W   = (const float*)d_in[21];
  const float* l1b   = (const float*)d_in[22];
  const float* l2W   = (const float*)d_in[23];
  const float* l2b   = (const float*)d_in[24];
  float* out = (float*)d_out;

  int N = in_sizes[0];
  int E = in_sizes[3]/2;
  int B = N/NPG;
  const int* src = eidx;
  const int* dst = eidx + E;

  char* p = (char*)d_ws;
  auto alloc = [&](size_t bytes)->char*{
    char* r = p;
    p += (bytes + 255) & ~(size_t)255;
    return r;
  };
  float* h1    = (float*)alloc((size_t)N*32*4);
  float* h2    = (float*)alloc((size_t)N*32*4);
  float* h3    = (float*)alloc((size_t)N*32*4);
  float* h4    = (float*)alloc((size_t)N*4);
  float* gx    = (float*)alloc((size_t)N*32*4);
  float* dis   = (float*)alloc((size_t)N*4);
  int*   rs    = (int*)  alloc((size_t)(N+1)*4);
  int*   histG = (int*)  alloc((size_t)NBLK*NB*4);
  int*   prefT = (int*)  alloc((size_t)NB*NBLK*4);
  int*   total = (int*)  alloc((size_t)NB*4);
  int*   bbase = (int*)  alloc((size_t)(NB+1)*4);
  int2*  csr   = (int2*) alloc((size_t)E*8);
  float* t2G   = (float*)alloc((size_t)B*480*4);
  int2*  ebuf  = (int2*)h1;    // alias: dead before h1 written

  k_hist   <<<NBLK, 256, 0, stream>>>(dst, histG, E);
  k_colscan<<<NB,  NBLK, 0, stream>>>(histG, prefT, total);
  k_bscan  <<<1,   1024, 0, stream>>>(total, bbase);
  k_scatter<<<NBLK, 256, 0, stream>>>(src, dst, ew, prefT, bbase, ebuf, E);
  k_bucket <<<B,    256, 0, stream>>>(ebuf, bbase, dis, rs, csr, N);

  int gG = (N+127)/128;
  int gA = (N+3)/4;
  k_gemm1 <<<gG, 256, 0, stream>>>(w, z1, z2, embw, embz1, embz2, W0, dis, gx, N);
  k_agg32 <<<gA, 256, 0, stream>>>(gx, dis, rs, csr, b0, h1, N);
  k_gemm32<<<gG, 256, 0, stream>>>(h1, W1, dis, gx, N);
  k_agg32 <<<gA, 256, 0, stream>>>(gx, dis, rs, csr, b1, h2, N);
  k_gemm32<<<gG, 256, 0, stream>>>(h2, W2, dis, gx, N);
  k_agg32 <<<gA, 256, 0, stream>>>(gx, dis, rs, csr, b2, h3, N);
  k_gemmv <<<(N+255)/256, 256, 0, stream>>>(h3, W3, dis, gx, N);
  k_agg1  <<<(N+255)/256, 256, 0, stream>>>(gx, dis, rs, csr, b3, h4, N);

  k_sortpool<<<B, 256, 0, stream>>>(h1, h2, h3, h4, c1W, c1b, t2G, N);
  k_tail    <<<B/8, 256, 0, stream>>>(t2G, c2W, c2b, l1W, l1b, l2W, l2b, out);
}

// Round 6
// 722.816 us; speedup vs baseline: 3.2783x; 1.1204x over previous
//
#include <hip/hip_runtime.h>
#include <math.h>

#define NPG 100
#define KTOP 60
#define DLAT 97
#define NC 250          // coarse buckets (8 graphs = 800 nodes each)
#define NODESC 800      // nodes per coarse bucket
#define NBLKA 1024      // binning blocks

static __device__ __forceinline__ float dot4(float4 a, float4 b){
  return a.x*b.x + a.y*b.y + a.z*b.z + a.w*b.w;
}

// ---------------- prep: two-level atomic-free CSR build ----------------
__global__ __launch_bounds__(256) void k_histA(const int* __restrict__ dst, int* __restrict__ histA,
    int E, int cpb){
  __shared__ int h[NC];
  int blk = blockIdx.x, tid = threadIdx.x;
  if(tid < NC) h[tid] = 0;
  __syncthreads();
  int e0 = blk*cpb, e1 = min(e0+cpb, E);
  for(int e=e0+tid; e<e1; e+=256) atomicAdd(&h[dst[e]/NODESC], 1);
  __syncthreads();
  if(tid < NC) histA[blk*NC + tid] = h[tid];
}

// block per coarse bucket: exclusive scan over binning blocks
__global__ __launch_bounds__(NBLKA) void k_colscanA(const int* __restrict__ histA,
    int* __restrict__ prefA, int* __restrict__ totalA){
  __shared__ int s[NBLKA];
  int c = blockIdx.x, t = threadIdx.x;
  int v = histA[t*NC + c];
  s[t] = v;
  __syncthreads();
  for(int off=1; off<NBLKA; off<<=1){
    int u = (t >= off) ? s[t-off] : 0;
    __syncthreads();
    s[t] += u;
    __syncthreads();
  }
  prefA[c*NBLKA + t] = s[t] - v;     // coalesced write
  if(t == NBLKA-1) totalA[c] = s[t];
}

__global__ __launch_bounds__(256) void k_bscanA(const int* __restrict__ totalA, int* __restrict__ cbase){
  __shared__ int s[256];
  int t = threadIdx.x;
  int v = (t < NC) ? totalA[t] : 0;
  s[t] = v;
  __syncthreads();
  for(int off=1; off<256; off<<=1){
    int u = (t >= off) ? s[t-off] : 0;
    __syncthreads();
    s[t] += u;
    __syncthreads();
  }
  if(t < NC) cbase[t] = s[t] - v;
  if(t == 255) cbase[NC] = s[255];
}

// coarse scatter: packed edge x = src | (dst%NODESC)<<18, y = bits of ew
__global__ __launch_bounds__(256) void k_scatterA(const int* __restrict__ src, const int* __restrict__ dst,
    const float* __restrict__ ew, const int* __restrict__ prefA, const int* __restrict__ cbase,
    int2* __restrict__ ebufA, int E, int cpb){
  __shared__ int cur[NC];
  int blk = blockIdx.x, tid = threadIdx.x;
  if(tid < NC) cur[tid] = prefA[tid*NBLKA + blk] + cbase[tid];
  __syncthreads();
  int e0 = blk*cpb, e1 = min(e0+cpb, E);
  for(int e=e0+tid; e<e1; e+=256){
    int d = dst[e];
    int c = d/NODESC;
    int dm = d - c*NODESC;
    int pos = atomicAdd(&cur[c], 1);          // LDS atomic
    ebufA[pos] = make_int2(src[e] | (dm<<18), __float_as_int(ew[e]));
  }
}

// block per coarse bucket: degree -> dis, row starts, scatter to final CSR
__global__ __launch_bounds__(1024) void k_bucket8(const int2* __restrict__ ebufA, const int* __restrict__ cbase,
    float* __restrict__ dis, int* __restrict__ rs, int2* __restrict__ csr, int N){
  __shared__ float degw[NODESC];
  __shared__ int cnt[NODESC];
  __shared__ int cur[NODESC];
  __shared__ int sc[1024];
  int c = blockIdx.x, tid = threadIdx.x;
  int n0 = c*NODESC;
  if(tid < NODESC){ degw[tid] = 0.f; cnt[tid] = 0; }
  __syncthreads();
  int e0 = cbase[c], e1 = cbase[c+1];
  for(int e=e0+tid; e<e1; e+=1024){
    int2 t = ebufA[e];
    int ld = ((unsigned)t.x)>>18;
    atomicAdd(&cnt[ld], 1);
    atomicAdd(&degw[ld], __int_as_float(t.y));
  }
  __syncthreads();
  if(tid < NODESC) dis[n0+tid] = rsqrtf(degw[tid] + 1.0f);
  sc[tid] = (tid < NODESC) ? cnt[tid] : 0;
  __syncthreads();
  for(int off=1; off<1024; off<<=1){
    int u = (tid >= off) ? sc[tid-off] : 0;
    __syncthreads();
    sc[tid] += u;
    __syncthreads();
  }
  if(tid < NODESC){
    int st = e0 + sc[tid] - cnt[tid];
    cur[tid] = st;
    rs[n0+tid] = st;
  }
  if(c == NC-1 && tid == 0) rs[N] = e1;
  __syncthreads();
  for(int e=e0+tid; e<e1; e+=1024){
    int2 t = ebufA[e];
    int ld = ((unsigned)t.x)>>18;
    int pos = atomicAdd(&cur[ld], 1);
    csr[pos] = make_int2(t.x & 0x3FFFF, t.y);
  }
}

// ---------------- GEMMs (row-major out, pre-scaled by dis[n]) ----------------
__global__ __launch_bounds__(256) void k_gemm1(const int* __restrict__ wI, const int* __restrict__ z1I,
   const int* __restrict__ z2I,
   const float* __restrict__ embw, const float* __restrict__ embz1, const float* __restrict__ embz2,
   const float* __restrict__ W0, const float* __restrict__ dis, float* __restrict__ gx, int N){
  __shared__ __align__(16) float X[128][97];
  __shared__ __align__(16) float Ws[96*32];
  __shared__ int iw[128], i1[128], i2[128];
  int tid = threadIdx.x;
  int g0 = blockIdx.x*128;
  for(int i=tid;i<768;i+=256) ((float4*)Ws)[i] = ((const float4*)W0)[i];
  if(tid < 128){
    int gn = g0 + tid;
    bool ok = gn < N;
    iw[tid] = ok ? wI[gn]  : 0;
    i1[tid] = ok ? z1I[gn] : 0;
    i2[tid] = ok ? z2I[gn] : 0;
  }
  __syncthreads();
  for(int r=0;r<48;r++){
    int flat = r*256 + tid;
    int n = flat/96, c = flat - n*96;
    int gn = g0 + n;
    float val = 0.f;
    if(gn < N){
      if(c < 32)      val = embw [iw[n]*32 + c];
      else if(c < 64) val = embz1[i1[n]*32 + (c-32)];
      else            val = embz2[i2[n]*32 + (c-64)];
    }
    X[n][c] = val;
  }
  __syncthreads();
  int ng = tid>>3, chg = tid&7;
  float4 acc[4];
  #pragma unroll
  for(int j=0;j<4;j++) acc[j] = make_float4(0.f,0.f,0.f,0.f);
  #pragma unroll 4
  for(int i=0;i<96;i++){
    float4 wv = *(const float4*)&Ws[i*32 + chg*4];
    #pragma unroll
    for(int j=0;j<4;j++){
      float xv = X[ng*4+j][i];
      acc[j].x += xv*wv.x; acc[j].y += xv*wv.y; acc[j].z += xv*wv.z; acc[j].w += xv*wv.w;
    }
  }
  #pragma unroll
  for(int j=0;j<4;j++){
    int gn = g0 + ng*4 + j;
    if(gn < N){
      float dv = dis[gn];
      acc[j].x *= dv; acc[j].y *= dv; acc[j].z *= dv; acc[j].w *= dv;
      *(float4*)&gx[(size_t)gn*32 + chg*4] = acc[j];
    }
  }
}

__global__ __launch_bounds__(256) void k_gemm32(const float* __restrict__ xin, const float* __restrict__ W,
    const float* __restrict__ dis, float* __restrict__ gx, int N){
  __shared__ __align__(16) float X[128][33];
  __shared__ __align__(16) float Ws[32*32];
  int tid = threadIdx.x;
  int g0 = blockIdx.x*128;
  ((float4*)Ws)[tid] = ((const float4*)W)[tid];
  for(int r=0;r<4;r++){
    int f = r*256 + tid;
    int n = f>>3, c4 = f&7;
    int gn = g0 + n;
    float4 v = (gn < N) ? ((const float4*)(xin + (size_t)gn*32))[c4] : make_float4(0,0,0,0);
    float* xr = &X[n][c4*4];
    xr[0]=v.x; xr[1]=v.y; xr[2]=v.z; xr[3]=v.w;
  }
  __syncthreads();
  int ng = tid>>3, chg = tid&7;
  float4 acc[4];
  #pragma unroll
  for(int j=0;j<4;j++) acc[j] = make_float4(0.f,0.f,0.f,0.f);
  #pragma unroll 4
  for(int i=0;i<32;i++){
    float4 wv = *(const float4*)&Ws[i*32 + chg*4];
    #pragma unroll
    for(int j=0;j<4;j++){
      float xv = X[ng*4+j][i];
      acc[j].x += xv*wv.x; acc[j].y += xv*wv.y; acc[j].z += xv*wv.z; acc[j].w += xv*wv.w;
    }
  }
  #pragma unroll
  for(int j=0;j<4;j++){
    int gn = g0 + ng*4 + j;
    if(gn < N){
      float dv = dis[gn];
      acc[j].x *= dv; acc[j].y *= dv; acc[j].z *= dv; acc[j].w *= dv;
      *(float4*)&gx[(size_t)gn*32 + chg*4] = acc[j];
    }
  }
}

__global__ __launch_bounds__(256) void k_gemmv(const float* __restrict__ xin, const float* __restrict__ W3,
    const float* __restrict__ dis, float* __restrict__ gv, int N){
  __shared__ float X[256][33];
  __shared__ float Ws[32];
  int tid = threadIdx.x;
  int g0 = blockIdx.x*256;
  if(tid < 32) Ws[tid] = W3[tid];
  for(int r=0;r<8;r++){
    int f = r*256 + tid;
    int n = f>>3, c4 = f&7;
    int gn = g0 + n;
    float4 v = (gn < N) ? ((const float4*)(xin + (size_t)gn*32))[c4] : make_float4(0,0,0,0);
    float* xr = &X[n][c4*4];
    xr[0]=v.x; xr[1]=v.y; xr[2]=v.z; xr[3]=v.w;
  }
  __syncthreads();
  float acc = 0.f;
  #pragma unroll
  for(int i=0;i<32;i++) acc += X[tid][i]*Ws[i];
  int gn = g0 + tid;
  if(gn < N) gv[gn] = acc*dis[gn];
}

// ---------------- aggregation: wave per dst node, 8 edges x 8 ch-groups ----------------
__global__ __launch_bounds__(256) void k_agg32(const float* __restrict__ g,
   const float* __restrict__ dis, const int* __restrict__ rs, const int2* __restrict__ csr,
   const float* __restrict__ bias, float* __restrict__ hout, int N){
  int wave = threadIdx.x >> 6;
  int lane = threadIdx.x & 63;
  int es = lane >> 3;
  int cg = lane & 7;
  int n = blockIdx.x*4 + wave;
  if(n >= N) return;
  int e0 = rs[n], e1 = rs[n+1];
  int deg = e1 - e0;
  int full = deg >> 3, rem = deg & 7;
  float4 acc = make_float4(0.f,0.f,0.f,0.f);
  int idx = e0 + es;
  for(int it=0; it<full; ++it){
    int2 p = csr[idx];
    float w = __int_as_float(p.y);
    float4 v = ((const float4*)(g + (size_t)p.x*32))[cg];
    acc.x += w*v.x; acc.y += w*v.y; acc.z += w*v.z; acc.w += w*v.w;
    idx += 8;
  }
  if(es < rem){
    int2 p = csr[idx];
    float w = __int_as_float(p.y);
    float4 v = ((const float4*)(g + (size_t)p.x*32))[cg];
    acc.x += w*v.x; acc.y += w*v.y; acc.z += w*v.z; acc.w += w*v.w;
  }
  #pragma unroll
  for(int off=8; off<64; off<<=1){
    acc.x += __shfl_xor(acc.x, off);
    acc.y += __shfl_xor(acc.y, off);
    acc.z += __shfl_xor(acc.z, off);
    acc.w += __shfl_xor(acc.w, off);
  }
  float4 self = ((const float4*)(g + (size_t)n*32))[cg];
  float dn = dis[n];
  float4 bv = ((const float4*)bias)[cg];
  if(es == 0){
    float4 o;
    o.x = tanhf(dn*(acc.x + self.x) + bv.x);
    o.y = tanhf(dn*(acc.y + self.y) + bv.y);
    o.z = tanhf(dn*(acc.z + self.z) + bv.z);
    o.w = tanhf(dn*(acc.w + self.w) + bv.w);
    ((float4*)(hout + (size_t)n*32))[cg] = o;
  }
}

__global__ void k_agg1(const float* __restrict__ gv, const float* __restrict__ dis,
   const int* __restrict__ rs, const int2* __restrict__ csr,
   const float* __restrict__ b3, float* __restrict__ h4, int N){
  int n = blockIdx.x*256 + threadIdx.x;
  if(n >= N) return;
  float acc = gv[n];
  int e0 = rs[n], e1 = rs[n+1];
  for(int e=e0;e<e1;e++){
    int2 p = csr[e];
    acc += __int_as_float(p.y)*gv[p.x];
  }
  h4[n] = tanhf(dis[n]*acc + b3[0]);
}

// ---------------- kA: per-graph sort + gather + conv1 + maxpool -> t2G[B][16][30] ----------------
__global__ __launch_bounds__(256) void k_sortpool(const float* __restrict__ h1,const float* __restrict__ h2,
  const float* __restrict__ h3,const float* __restrict__ h4,
  const float* __restrict__ c1W,const float* __restrict__ c1b,
  float* __restrict__ t2G, int N){
  __shared__ float v[128];
  __shared__ int ord[KTOP];
  __shared__ __align__(16) float xk[KTOP][100];
  __shared__ __align__(16) float c1Ws[16*100];
  __shared__ __align__(16) float t2s[480];
  int b = blockIdx.x, tid = threadIdx.x;
  int g0 = b*NPG;
  for(int i=tid;i<16*97;i+=256){ int o=i/97, d=i-o*97; c1Ws[o*100+d]=c1W[i]; }
  if(tid < 100) v[tid] = h4[g0+tid];
  __syncthreads();
  if(tid < 100){
    float vi = v[tid];
    int rank = 0;
    for(int j=0;j<100;j++){
      float vj = v[j];
      rank += (vj > vi) || (vj == vi && j < tid);
    }
    if(rank < KTOP) ord[rank] = tid;
  }
  __syncthreads();
  for(int idx=tid; idx<KTOP*DLAT; idx+=256){
    int k = idx/DLAT, d = idx - k*DLAT;
    int n = g0 + ord[k];
    float val;
    if(d < 96){
      const float* hsrc = (d<32) ? h1 : (d<64) ? h2 : h3;
      val = hsrc[(size_t)n*32 + (d&31)];
    } else val = h4[n];
    xk[k][d] = val;
  }
  __syncthreads();
  {
    int og = tid & 7, j = tid >> 3;
    if(j < 30){
      int k0 = 2*j, k1 = 2*j+1;
      float a00=0.f, a01=0.f, a10=0.f, a11=0.f;
      for(int d=0; d<96; d+=4){
        float4 w0 = *(const float4*)&c1Ws[og*100 + d];
        float4 w1 = *(const float4*)&c1Ws[(og+8)*100 + d];
        float4 x0 = *(const float4*)&xk[k0][d];
        float4 x1 = *(const float4*)&xk[k1][d];
        a00 += dot4(x0, w0); a01 += dot4(x1, w0);
        a10 += dot4(x0, w1); a11 += dot4(x1, w1);
      }
      {
        float w0 = c1Ws[og*100 + 96], w1 = c1Ws[(og+8)*100 + 96];
        float x0 = xk[k0][96], x1 = xk[k1][96];
        a00 += x0*w0; a01 += x1*w0;
        a10 += x0*w1; a11 += x1*w1;
      }
      float b0v = c1b[og], b1v = c1b[og+8];
      float r0 = fmaxf(fmaxf(a00+b0v,0.f), fmaxf(a01+b0v,0.f));
      float r1 = fmaxf(fmaxf(a10+b1v,0.f), fmaxf(a11+b1v,0.f));
      t2s[og*30 + j] = r0;
      t2s[(og+8)*30 + j] = r1;
    }
  }
  __syncthreads();
  if(tid < 120) ((float4*)&t2G[(size_t)b*480])[tid] = ((const float4*)t2s)[tid];
}

// ---------------- kB: conv2 + l1 + l2, 8 graphs per block ----------------
__global__ __launch_bounds__(256) void k_tail(const float* __restrict__ t2G,
  const float* __restrict__ c2W,const float* __restrict__ c2b,
  const float* __restrict__ l1W,const float* __restrict__ l1b,
  const float* __restrict__ l2W,const float* __restrict__ l2b,
  float* __restrict__ out){
  __shared__ __align__(16) float t2s[8*480];
  __shared__ __align__(16) float c2Ws[2560];
  __shared__ __align__(16) float flat[8][832];
  __shared__ __align__(16) float o1s[8][128];
  int bG = blockIdx.x, tid = threadIdx.x;
  for(int i=tid; i<960; i+=256) ((float4*)t2s)[i] = ((const float4*)(t2G + (size_t)bG*8*480))[i];
  for(int i=tid; i<640; i+=256) ((float4*)c2Ws)[i] = ((const float4*)c2W)[i];
  __syncthreads();
  {
    int g = tid >> 5, oc = tid & 31;
    float acc[26];
    #pragma unroll
    for(int p=0;p<26;p++) acc[p]=0.f;
    for(int ic=0; ic<16; ic++){
      const float* trow = &t2s[g*480 + ic*30];
      float t[30];
      #pragma unroll
      for(int p=0;p<30;p++) t[p] = trow[p];
      const float* wr = &c2Ws[(oc*16 + ic)*5];
      float w0=wr[0], w1=wr[1], w2=wr[2], w3=wr[3], w4=wr[4];
      #pragma unroll
      for(int p=0;p<26;p++)
        acc[p] += t[p]*w0 + t[p+1]*w1 + t[p+2]*w2 + t[p+3]*w3 + t[p+4]*w4;
    }
    float bb = c2b[oc];
    #pragma unroll
    for(int p=0;p<26;p++) flat[g][oc*26+p] = fmaxf(acc[p]+bb, 0.f);
  }
  __syncthreads();
  {
    int j = tid & 127, gq = tid >> 7;
    float acc0=0.f, acc1=0.f, acc2=0.f, acc3=0.f;
    const float* f0 = flat[gq*4+0];
    const float* f1 = flat[gq*4+1];
    const float* f2 = flat[gq*4+2];
    const float* f3 = flat[gq*4+3];
    for(int i4=0; i4<208; i4++){
      int i = i4*4;
      float w0 = l1W[(size_t)i*128 + j];
      float w1 = l1W[(size_t)(i+1)*128 + j];
      float w2 = l1W[(size_t)(i+2)*128 + j];
      float w3 = l1W[(size_t)(i+3)*128 + j];
      float4 a0 = *(const float4*)&f0[i];
      float4 a1 = *(const float4*)&f1[i];
      float4 a2 = *(const float4*)&f2[i];
      float4 a3 = *(const float4*)&f3[i];
      acc0 += a0.x*w0 + a0.y*w1 + a0.z*w2 + a0.w*w3;
      acc1 += a1.x*w0 + a1.y*w1 + a1.z*w2 + a1.w*w3;
      acc2 += a2.x*w0 + a2.y*w1 + a2.z*w2 + a2.w*w3;
      acc3 += a3.x*w0 + a3.y*w1 + a3.z*w2 + a3.w*w3;
    }
    o1s[gq*4+0][j] = acc0;
    o1s[gq*4+1][j] = acc1;
    o1s[gq*4+2][j] = acc2;
    o1s[gq*4+3][j] = acc3;
  }
  __syncthreads();
  {
    int g = tid >> 5, jj = tid & 31;
    float s = 0.f;
    #pragma unroll
    for(int q=0;q<4;q++){
      int j = jj + 32*q;
      float r = fmaxf(o1s[g][j] + l1b[j], 0.f);
      s += r * l2W[j];
    }
    #pragma unroll
    for(int off=16; off>0; off>>=1) s += __shfl_xor(s, off);
    if(jj == 0) out[bG*8 + g] = s + l2b[0];
  }
}

// ---------------- launch ----------------
extern "C" void kernel_launch(void* const* d_in, const int* in_sizes, int n_in,
                              void* d_out, int out_size, void* d_ws, size_t ws_size,
                              hipStream_t stream){
  (void)n_in; (void)out_size; (void)ws_size;
  const int*   z1    = (const int*)  d_in[0];
  const int*   z2    = (const int*)  d_in[1];
  const int*   w     = (const int*)  d_in[2];
  const int*   eidx  = (const int*)  d_in[3];
  const float* ew    = (const float*)d_in[5];
  const float* embw  = (const float*)d_in[6];
  const float* embz1 = (const float*)d_in[7];
  const float* embz2 = (const float*)d_in[8];
  const float* W0    = (const float*)d_in[9];
  const float* b0    = (const float*)d_in[10];
  const float* W1    = (const float*)d_in[11];
  const float* b1    = (const float*)d_in[12];
  const float* W2    = (const float*)d_in[13];
  const float* b2    = (const float*)d_in[14];
  const float* W3    = (const float*)d_in[15];
  const float* b3    = (const float*)d_in[16];
  const float* c1W   = (const float*)d_in[17];
  const float* c1b   = (const float*)d_in[18];
  const float* c2W   = (const float*)d_in[19];
  const float* c2b   = (const float*)d_in[20];
  const float* l1W   = (const float*)d_in[21];
  const float* l1b   = (const float*)d_in[22];
  const float* l2W   = (const float*)d_in[23];
  const float* l2b   = (const float*)d_in[24];
  float* out = (float*)d_out;

  int N = in_sizes[0];
  int E = in_sizes[3]/2;
  int B = N/NPG;
  const int* src = eidx;
  const int* dst = eidx + E;

  char* p = (char*)d_ws;
  auto alloc = [&](size_t bytes)->char*{
    char* r = p;
    p += (bytes + 255) & ~(size_t)255;
    return r;
  };
  float* h1    = (float*)alloc((size_t)N*32*4);
  float* h2    = (float*)alloc((size_t)N*32*4);
  float* h3    = (float*)alloc((size_t)N*32*4);
  float* h4    = (float*)alloc((size_t)N*4);
  float* gx    = (float*)alloc((size_t)N*32*4);
  float* dis   = (float*)alloc((size_t)N*4);
  int*   rs    = (int*)  alloc((size_t)(N+1)*4);
  int*   histA = (int*)  alloc((size_t)NBLKA*NC*4);
  int*   prefA = (int*)  alloc((size_t)NC*NBLKA*4);
  int*   totalA= (int*)  alloc((size_t)NC*4);
  int*   cbase = (int*)  alloc((size_t)(NC+1)*4);
  int2*  csr   = (int2*) alloc((size_t)E*8);
  float* t2G   = (float*)alloc((size_t)B*480*4);
  int2*  ebufA = (int2*)h1;    // alias: dead before h1 written

  int cpb = (E + NBLKA - 1)/NBLKA;
  k_histA   <<<NBLKA, 256, 0, stream>>>(dst, histA, E, cpb);
  k_colscanA<<<NC, NBLKA, 0, stream>>>(histA, prefA, totalA);
  k_bscanA  <<<1,    256, 0, stream>>>(totalA, cbase);
  k_scatterA<<<NBLKA, 256, 0, stream>>>(src, dst, ew, prefA, cbase, ebufA, E, cpb);
  k_bucket8 <<<NC,  1024, 0, stream>>>(ebufA, cbase, dis, rs, csr, N);

  int gG = (N+127)/128;
  int gA = (N+3)/4;
  k_gemm1 <<<gG, 256, 0, stream>>>(w, z1, z2, embw, embz1, embz2, W0, dis, gx, N);
  k_agg32 <<<gA, 256, 0, stream>>>(gx, dis, rs, csr, b0, h1, N);
  k_gemm32<<<gG, 256, 0, stream>>>(h1, W1, dis, gx, N);
  k_agg32 <<<gA, 256, 0, stream>>>(gx, dis, rs, csr, b1, h2, N);
  k_gemm32<<<gG, 256, 0, stream>>>(h2, W2, dis, gx, N);
  k_agg32 <<<gA, 256, 0, stream>>>(gx, dis, rs, csr, b2, h3, N);
  k_gemmv <<<(N+255)/256, 256, 0, stream>>>(h3, W3, dis, gx, N);
  k_agg1  <<<(N+255)/256, 256, 0, stream>>>(gx, dis, rs, csr, b3, h4, N);

  k_sortpool<<<B, 256, 0, stream>>>(h1, h2, h3, h4, c1W, c1b, t2G, N);
  k_tail    <<<B/8, 256, 0, stream>>>(t2G, c2W, c2b, l1W, l1b, l2W, l2b, out);
}

// Round 7
// 691.942 us; speedup vs baseline: 3.4245x; 1.0446x over previous
//
#include <hip/hip_runtime.h>
#include <math.h>

#define NPG 100
#define KTOP 60
#define DLAT 97
#define NC 250          // coarse buckets (8 graphs = 800 nodes each)
#define NODESC 800      // nodes per coarse bucket
#define NBLKA 1024      // binning blocks

static __device__ __forceinline__ float dot4(float4 a, float4 b){
  return a.x*b.x + a.y*b.y + a.z*b.z + a.w*b.w;
}

// ---------------- prep: two-level atomic-free CSR build ----------------
__global__ __launch_bounds__(256) void k_histA(const int* __restrict__ dst, int* __restrict__ histA,
    int E, int cpb){
  __shared__ int h[NC];
  int blk = blockIdx.x, tid = threadIdx.x;
  if(tid < NC) h[tid] = 0;
  __syncthreads();
  int e0 = blk*cpb, e1 = min(e0+cpb, E);
  for(int e=e0+tid; e<e1; e+=256) atomicAdd(&h[dst[e]/NODESC], 1);
  __syncthreads();
  if(tid < NC) histA[blk*NC + tid] = h[tid];
}

__global__ __launch_bounds__(NBLKA) void k_colscanA(const int* __restrict__ histA,
    int* __restrict__ prefA, int* __restrict__ totalA){
  __shared__ int s[NBLKA];
  int c = blockIdx.x, t = threadIdx.x;
  int v = histA[t*NC + c];
  s[t] = v;
  __syncthreads();
  for(int off=1; off<NBLKA; off<<=1){
    int u = (t >= off) ? s[t-off] : 0;
    __syncthreads();
    s[t] += u;
    __syncthreads();
  }
  prefA[c*NBLKA + t] = s[t] - v;
  if(t == NBLKA-1) totalA[c] = s[t];
}

__global__ __launch_bounds__(256) void k_bscanA(const int* __restrict__ totalA, int* __restrict__ cbase){
  __shared__ int s[256];
  int t = threadIdx.x;
  int v = (t < NC) ? totalA[t] : 0;
  s[t] = v;
  __syncthreads();
  for(int off=1; off<256; off<<=1){
    int u = (t >= off) ? s[t-off] : 0;
    __syncthreads();
    s[t] += u;
    __syncthreads();
  }
  if(t < NC) cbase[t] = s[t] - v;
  if(t == 255) cbase[NC] = s[255];
}

__global__ __launch_bounds__(256) void k_scatterA(const int* __restrict__ src, const int* __restrict__ dst,
    const float* __restrict__ ew, const int* __restrict__ prefA, const int* __restrict__ cbase,
    int2* __restrict__ ebufA, int E, int cpb){
  __shared__ int cur[NC];
  int blk = blockIdx.x, tid = threadIdx.x;
  if(tid < NC) cur[tid] = prefA[tid*NBLKA + blk] + cbase[tid];
  __syncthreads();
  int e0 = blk*cpb, e1 = min(e0+cpb, E);
  for(int e=e0+tid; e<e1; e+=256){
    int d = dst[e];
    int c = d/NODESC;
    int dm = d - c*NODESC;
    int pos = atomicAdd(&cur[c], 1);          // LDS atomic
    ebufA[pos] = make_int2(src[e] | (dm<<18), __float_as_int(ew[e]));
  }
}

__global__ __launch_bounds__(1024) void k_bucket8(const int2* __restrict__ ebufA, const int* __restrict__ cbase,
    float* __restrict__ dis, int* __restrict__ rs, int2* __restrict__ csr, int N){
  __shared__ float degw[NODESC];
  __shared__ int cnt[NODESC];
  __shared__ int cur[NODESC];
  __shared__ int sc[1024];
  int c = blockIdx.x, tid = threadIdx.x;
  int n0 = c*NODESC;
  if(tid < NODESC){ degw[tid] = 0.f; cnt[tid] = 0; }
  __syncthreads();
  int e0 = cbase[c], e1 = cbase[c+1];
  for(int e=e0+tid; e<e1; e+=1024){
    int2 t = ebufA[e];
    int ld = ((unsigned)t.x)>>18;
    atomicAdd(&cnt[ld], 1);
    atomicAdd(&degw[ld], __int_as_float(t.y));
  }
  __syncthreads();
  if(tid < NODESC) dis[n0+tid] = rsqrtf(degw[tid] + 1.0f);
  sc[tid] = (tid < NODESC) ? cnt[tid] : 0;
  __syncthreads();
  for(int off=1; off<1024; off<<=1){
    int u = (tid >= off) ? sc[tid-off] : 0;
    __syncthreads();
    sc[tid] += u;
    __syncthreads();
  }
  if(tid < NODESC){
    int st = e0 + sc[tid] - cnt[tid];
    cur[tid] = st;
    rs[n0+tid] = st;
  }
  if(c == NC-1 && tid == 0) rs[N] = e1;
  __syncthreads();
  for(int e=e0+tid; e<e1; e+=1024){
    int2 t = ebufA[e];
    int ld = ((unsigned)t.x)>>18;
    int pos = atomicAdd(&cur[ld], 1);
    csr[pos] = make_int2(t.x & 0x3FFFF, t.y);
  }
}

// ---------------- GEMMs (row-major out, pre-scaled by dis[n]) ----------------
__global__ __launch_bounds__(256) void k_gemm1(const int* __restrict__ wI, const int* __restrict__ z1I,
   const int* __restrict__ z2I,
   const float* __restrict__ embw, const float* __restrict__ embz1, const float* __restrict__ embz2,
   const float* __restrict__ W0, const float* __restrict__ dis, float* __restrict__ gx, int N){
  __shared__ __align__(16) float X[128][97];
  __shared__ __align__(16) float Ws[96*32];
  __shared__ int iw[128], i1[128], i2[128];
  int tid = threadIdx.x;
  int g0 = blockIdx.x*128;
  for(int i=tid;i<768;i+=256) ((float4*)Ws)[i] = ((const float4*)W0)[i];
  if(tid < 128){
    int gn = g0 + tid;
    bool ok = gn < N;
    iw[tid] = ok ? wI[gn]  : 0;
    i1[tid] = ok ? z1I[gn] : 0;
    i2[tid] = ok ? z2I[gn] : 0;
  }
  __syncthreads();
  for(int r=0;r<48;r++){
    int flat = r*256 + tid;
    int n = flat/96, c = flat - n*96;
    int gn = g0 + n;
    float val = 0.f;
    if(gn < N){
      if(c < 32)      val = embw [iw[n]*32 + c];
      else if(c < 64) val = embz1[i1[n]*32 + (c-32)];
      else            val = embz2[i2[n]*32 + (c-64)];
    }
    X[n][c] = val;
  }
  __syncthreads();
  int ng = tid>>3, chg = tid&7;
  float4 acc[4];
  #pragma unroll
  for(int j=0;j<4;j++) acc[j] = make_float4(0.f,0.f,0.f,0.f);
  #pragma unroll 4
  for(int i=0;i<96;i++){
    float4 wv = *(const float4*)&Ws[i*32 + chg*4];
    #pragma unroll
    for(int j=0;j<4;j++){
      float xv = X[ng*4+j][i];
      acc[j].x += xv*wv.x; acc[j].y += xv*wv.y; acc[j].z += xv*wv.z; acc[j].w += xv*wv.w;
    }
  }
  #pragma unroll
  for(int j=0;j<4;j++){
    int gn = g0 + ng*4 + j;
    if(gn < N){
      float dv = dis[gn];
      acc[j].x *= dv; acc[j].y *= dv; acc[j].z *= dv; acc[j].w *= dv;
      *(float4*)&gx[(size_t)gn*32 + chg*4] = acc[j];
    }
  }
}

__global__ __launch_bounds__(256) void k_gemm32(const float* __restrict__ xin, const float* __restrict__ W,
    const float* __restrict__ dis, float* __restrict__ gx, int N){
  __shared__ __align__(16) float X[128][33];
  __shared__ __align__(16) float Ws[32*32];
  int tid = threadIdx.x;
  int g0 = blockIdx.x*128;
  ((float4*)Ws)[tid] = ((const float4*)W)[tid];
  for(int r=0;r<4;r++){
    int f = r*256 + tid;
    int n = f>>3, c4 = f&7;
    int gn = g0 + n;
    float4 v = (gn < N) ? ((const float4*)(xin + (size_t)gn*32))[c4] : make_float4(0,0,0,0);
    float* xr = &X[n][c4*4];
    xr[0]=v.x; xr[1]=v.y; xr[2]=v.z; xr[3]=v.w;
  }
  __syncthreads();
  int ng = tid>>3, chg = tid&7;
  float4 acc[4];
  #pragma unroll
  for(int j=0;j<4;j++) acc[j] = make_float4(0.f,0.f,0.f,0.f);
  #pragma unroll 4
  for(int i=0;i<32;i++){
    float4 wv = *(const float4*)&Ws[i*32 + chg*4];
    #pragma unroll
    for(int j=0;j<4;j++){
      float xv = X[ng*4+j][i];
      acc[j].x += xv*wv.x; acc[j].y += xv*wv.y; acc[j].z += xv*wv.z; acc[j].w += xv*wv.w;
    }
  }
  #pragma unroll
  for(int j=0;j<4;j++){
    int gn = g0 + ng*4 + j;
    if(gn < N){
      float dv = dis[gn];
      acc[j].x *= dv; acc[j].y *= dv; acc[j].z *= dv; acc[j].w *= dv;
      *(float4*)&gx[(size_t)gn*32 + chg*4] = acc[j];
    }
  }
}

// ---------------- aggregation: wave per dst node, 8 edges x 8 ch-groups, pipelined ----------------
__global__ __launch_bounds__(256) void k_agg32(const float* __restrict__ g,
   const float* __restrict__ dis, const int* __restrict__ rs, const int2* __restrict__ csr,
   const float* __restrict__ bias, float* __restrict__ hout, int N){
  int wave = threadIdx.x >> 6;
  int lane = threadIdx.x & 63;
  int es = lane >> 3;
  int cg = lane & 7;
  int n = blockIdx.x*4 + wave;
  if(n >= N) return;
  int e0 = rs[n], e1 = rs[n+1];
  int deg = e1 - e0;
  int iters = (deg + 7) >> 3;
  float4 acc = make_float4(0.f,0.f,0.f,0.f);
  int e = e0 + es;
  int2 p = (e < e1) ? csr[e] : make_int2(0,0);   // w=0 pad: contributes exactly 0
  for(int it=0; it<iters; ++it){
    int s = p.x;
    float w = __int_as_float(p.y);
    e += 8;
    int2 pn = (e < e1) ? csr[e] : make_int2(0,0); // prefetch next csr before dependent gx load
    float4 v = ((const float4*)(g + (size_t)s*32))[cg];
    acc.x += w*v.x; acc.y += w*v.y; acc.z += w*v.z; acc.w += w*v.w;
    p = pn;
  }
  #pragma unroll
  for(int off=8; off<64; off<<=1){
    acc.x += __shfl_xor(acc.x, off);
    acc.y += __shfl_xor(acc.y, off);
    acc.z += __shfl_xor(acc.z, off);
    acc.w += __shfl_xor(acc.w, off);
  }
  float4 self = ((const float4*)(g + (size_t)n*32))[cg];
  float dn = dis[n];
  float4 bv = ((const float4*)bias)[cg];
  if(es == 0){
    float4 o;
    o.x = tanhf(dn*(acc.x + self.x) + bv.x);
    o.y = tanhf(dn*(acc.y + self.y) + bv.y);
    o.z = tanhf(dn*(acc.z + self.z) + bv.z);
    o.w = tanhf(dn*(acc.w + self.w) + bv.w);
    ((float4*)(hout + (size_t)n*32))[cg] = o;
  }
}

// layer-3 variant: also emits gv[n] = (h3 . W3) * dis[n]  (fused gemmv)
__global__ __launch_bounds__(256) void k_agg32v(const float* __restrict__ g,
   const float* __restrict__ dis, const int* __restrict__ rs, const int2* __restrict__ csr,
   const float* __restrict__ bias, const float* __restrict__ W3,
   float* __restrict__ hout, float* __restrict__ gv, int N){
  int wave = threadIdx.x >> 6;
  int lane = threadIdx.x & 63;
  int es = lane >> 3;
  int cg = lane & 7;
  int n = blockIdx.x*4 + wave;
  if(n >= N) return;
  int e0 = rs[n], e1 = rs[n+1];
  int deg = e1 - e0;
  int iters = (deg + 7) >> 3;
  float4 acc = make_float4(0.f,0.f,0.f,0.f);
  int e = e0 + es;
  int2 p = (e < e1) ? csr[e] : make_int2(0,0);
  for(int it=0; it<iters; ++it){
    int s = p.x;
    float w = __int_as_float(p.y);
    e += 8;
    int2 pn = (e < e1) ? csr[e] : make_int2(0,0);
    float4 v = ((const float4*)(g + (size_t)s*32))[cg];
    acc.x += w*v.x; acc.y += w*v.y; acc.z += w*v.z; acc.w += w*v.w;
    p = pn;
  }
  #pragma unroll
  for(int off=8; off<64; off<<=1){
    acc.x += __shfl_xor(acc.x, off);
    acc.y += __shfl_xor(acc.y, off);
    acc.z += __shfl_xor(acc.z, off);
    acc.w += __shfl_xor(acc.w, off);
  }
  float4 self = ((const float4*)(g + (size_t)n*32))[cg];
  float dn = dis[n];
  float4 bv = ((const float4*)bias)[cg];
  if(es == 0){
    float4 o;
    o.x = tanhf(dn*(acc.x + self.x) + bv.x);
    o.y = tanhf(dn*(acc.y + self.y) + bv.y);
    o.z = tanhf(dn*(acc.z + self.z) + bv.z);
    o.w = tanhf(dn*(acc.w + self.w) + bv.w);
    ((float4*)(hout + (size_t)n*32))[cg] = o;
    float4 w3v = *(const float4*)&W3[cg*4];
    float s = dot4(o, w3v);
    s += __shfl_xor(s, 1);
    s += __shfl_xor(s, 2);
    s += __shfl_xor(s, 4);
    if(cg == 0) gv[n] = s*dn;
  }
}

// ---------------- kA: fused agg1 + sort + gather + conv1 + maxpool -> t2G[B][16][30] ----------------
__global__ __launch_bounds__(256) void k_sortpool(const float* __restrict__ gv,
  const float* __restrict__ dis, const int* __restrict__ rs, const int2* __restrict__ csr,
  const float* __restrict__ b3,
  const float* __restrict__ h1,const float* __restrict__ h2,const float* __restrict__ h3,
  const float* __restrict__ c1W,const float* __restrict__ c1b,
  float* __restrict__ t2G, int N){
  __shared__ float v[128];
  __shared__ int ord[KTOP];
  __shared__ __align__(16) float xk[KTOP][100];
  __shared__ __align__(16) float c1Ws[16*100];
  __shared__ __align__(16) float t2s[480];
  int b = blockIdx.x, tid = threadIdx.x;
  int g0 = b*NPG;
  for(int i=tid;i<16*97;i+=256){ int o=i/97, d=i-o*97; c1Ws[o*100+d]=c1W[i]; }
  // fused agg1: h4 for this graph's 100 nodes (gv is globally complete)
  if(tid < 100){
    int n = g0 + tid;
    float acc = gv[n];
    int e0 = rs[n], e1 = rs[n+1];
    for(int e=e0;e<e1;e++){
      int2 p = csr[e];
      acc += __int_as_float(p.y)*gv[p.x];
    }
    v[tid] = tanhf(dis[n]*acc + b3[0]);
  }
  __syncthreads();
  // stable descending rank == argsort(-v) stable
  if(tid < 100){
    float vi = v[tid];
    int rank = 0;
    for(int j=0;j<100;j++){
      float vj = v[j];
      rank += (vj > vi) || (vj == vi && j < tid);
    }
    if(rank < KTOP) ord[rank] = tid;
  }
  __syncthreads();
  for(int idx=tid; idx<KTOP*DLAT; idx+=256){
    int k = idx/DLAT, d = idx - k*DLAT;
    int nk = ord[k];
    float val;
    if(d < 96){
      const float* hsrc = (d<32) ? h1 : (d<64) ? h2 : h3;
      val = hsrc[(size_t)(g0+nk)*32 + (d&31)];
    } else val = v[nk];
    xk[k][d] = val;
  }
  __syncthreads();
  {
    int og = tid & 7, j = tid >> 3;
    if(j < 30){
      int k0 = 2*j, k1 = 2*j+1;
      float a00=0.f, a01=0.f, a10=0.f, a11=0.f;
      for(int d=0; d<96; d+=4){
        float4 w0 = *(const float4*)&c1Ws[og*100 + d];
        float4 w1 = *(const float4*)&c1Ws[(og+8)*100 + d];
        float4 x0 = *(const float4*)&xk[k0][d];
        float4 x1 = *(const float4*)&xk[k1][d];
        a00 += dot4(x0, w0); a01 += dot4(x1, w0);
        a10 += dot4(x0, w1); a11 += dot4(x1, w1);
      }
      {
        float w0 = c1Ws[og*100 + 96], w1 = c1Ws[(og+8)*100 + 96];
        float x0 = xk[k0][96], x1 = xk[k1][96];
        a00 += x0*w0; a01 += x1*w0;
        a10 += x0*w1; a11 += x1*w1;
      }
      float b0v = c1b[og], b1v = c1b[og+8];
      float r0 = fmaxf(fmaxf(a00+b0v,0.f), fmaxf(a01+b0v,0.f));
      float r1 = fmaxf(fmaxf(a10+b1v,0.f), fmaxf(a11+b1v,0.f));
      t2s[og*30 + j] = r0;
      t2s[(og+8)*30 + j] = r1;
    }
  }
  __syncthreads();
  if(tid < 120) ((float4*)&t2G[(size_t)b*480])[tid] = ((const float4*)t2s)[tid];
}

// ---------------- kB: conv2 + l1 + l2, 8 graphs per block ----------------
__global__ __launch_bounds__(256) void k_tail(const float* __restrict__ t2G,
  const float* __restrict__ c2W,const float* __restrict__ c2b,
  const float* __restrict__ l1W,const float* __restrict__ l1b,
  const float* __restrict__ l2W,const float* __restrict__ l2b,
  float* __restrict__ out){
  __shared__ __align__(16) float t2s[8*480];
  __shared__ __align__(16) float c2Ws[2560];
  __shared__ __align__(16) float flat[8][832];
  __shared__ __align__(16) float o1s[8][128];
  int bG = blockIdx.x, tid = threadIdx.x;
  for(int i=tid; i<960; i+=256) ((float4*)t2s)[i] = ((const float4*)(t2G + (size_t)bG*8*480))[i];
  for(int i=tid; i<640; i+=256) ((float4*)c2Ws)[i] = ((const float4*)c2W)[i];
  __syncthreads();
  {
    int g = tid >> 5, oc = tid & 31;
    float acc[26];
    #pragma unroll
    for(int p=0;p<26;p++) acc[p]=0.f;
    for(int ic=0; ic<16; ic++){
      const float* trow = &t2s[g*480 + ic*30];
      float t[30];
      #pragma unroll
      for(int p=0;p<30;p++) t[p] = trow[p];
      const float* wr = &c2Ws[(oc*16 + ic)*5];
      float w0=wr[0], w1=wr[1], w2=wr[2], w3=wr[3], w4=wr[4];
      #pragma unroll
      for(int p=0;p<26;p++)
        acc[p] += t[p]*w0 + t[p+1]*w1 + t[p+2]*w2 + t[p+3]*w3 + t[p+4]*w4;
    }
    float bb = c2b[oc];
    #pragma unroll
    for(int p=0;p<26;p++) flat[g][oc*26+p] = fmaxf(acc[p]+bb, 0.f);
  }
  __syncthreads();
  {
    int j = tid & 127, gq = tid >> 7;
    float acc0=0.f, acc1=0.f, acc2=0.f, acc3=0.f;
    const float* f0 = flat[gq*4+0];
    const float* f1 = flat[gq*4+1];
    const float* f2 = flat[gq*4+2];
    const float* f3 = flat[gq*4+3];
    for(int i4=0; i4<208; i4++){
      int i = i4*4;
      float w0 = l1W[(size_t)i*128 + j];
      float w1 = l1W[(size_t)(i+1)*128 + j];
      float w2 = l1W[(size_t)(i+2)*128 + j];
      float w3 = l1W[(size_t)(i+3)*128 + j];
      float4 a0 = *(const float4*)&f0[i];
      float4 a1 = *(const float4*)&f1[i];
      float4 a2 = *(const float4*)&f2[i];
      float4 a3 = *(const float4*)&f3[i];
      acc0 += a0.x*w0 + a0.y*w1 + a0.z*w2 + a0.w*w3;
      acc1 += a1.x*w0 + a1.y*w1 + a1.z*w2 + a1.w*w3;
      acc2 += a2.x*w0 + a2.y*w1 + a2.z*w2 + a2.w*w3;
      acc3 += a3.x*w0 + a3.y*w1 + a3.z*w2 + a3.w*w3;
    }
    o1s[gq*4+0][j] = acc0;
    o1s[gq*4+1][j] = acc1;
    o1s[gq*4+2][j] = acc2;
    o1s[gq*4+3][j] = acc3;
  }
  __syncthreads();
  {
    int g = tid >> 5, jj = tid & 31;
    float s = 0.f;
    #pragma unroll
    for(int q=0;q<4;q++){
      int j = jj + 32*q;
      float r = fmaxf(o1s[g][j] + l1b[j], 0.f);
      s += r * l2W[j];
    }
    #pragma unroll
    for(int off=16; off>0; off>>=1) s += __shfl_xor(s, off);
    if(jj == 0) out[bG*8 + g] = s + l2b[0];
  }
}

// ---------------- launch ----------------
extern "C" void kernel_launch(void* const* d_in, const int* in_sizes, int n_in,
                              void* d_out, int out_size, void* d_ws, size_t ws_size,
                              hipStream_t stream){
  (void)n_in; (void)out_size; (void)ws_size;
  const int*   z1    = (const int*)  d_in[0];
  const int*   z2    = (const int*)  d_in[1];
  const int*   w     = (const int*)  d_in[2];
  const int*   eidx  = (const int*)  d_in[3];
  const float* ew    = (const float*)d_in[5];
  const float* embw  = (const float*)d_in[6];
  const float* embz1 = (const float*)d_in[7];
  const float* embz2 = (const float*)d_in[8];
  const float* W0    = (const float*)d_in[9];
  const float* b0    = (const float*)d_in[10];
  const float* W1    = (const float*)d_in[11];
  const float* b1    = (const float*)d_in[12];
  const float* W2    = (const float*)d_in[13];
  const float* b2    = (const float*)d_in[14];
  const float* W3    = (const float*)d_in[15];
  const float* b3    = (const float*)d_in[16];
  const float* c1W   = (const float*)d_in[17];
  const float* c1b   = (const float*)d_in[18];
  const float* c2W   = (const float*)d_in[19];
  const float* c2b   = (const float*)d_in[20];
  const float* l1W   = (const float*)d_in[21];
  const float* l1b   = (const float*)d_in[22];
  const float* l2W   = (const float*)d_in[23];
  const float* l2b   = (const float*)d_in[24];
  float* out = (float*)d_out;

  int N = in_sizes[0];
  int E = in_sizes[3]/2;
  int B = N/NPG;
  const int* src = eidx;
  const int* dst = eidx + E;

  char* p = (char*)d_ws;
  auto alloc = [&](size_t bytes)->char*{
    char* r = p;
    p += (bytes + 255) & ~(size_t)255;
    return r;
  };
  float* h1    = (float*)alloc((size_t)N*32*4);
  float* h2    = (float*)alloc((size_t)N*32*4);
  float* h3    = (float*)alloc((size_t)N*32*4);
  float* gv    = (float*)alloc((size_t)N*4);
  float* gx    = (float*)alloc((size_t)N*32*4);
  float* dis   = (float*)alloc((size_t)N*4);
  int*   rs    = (int*)  alloc((size_t)(N+1)*4);
  int*   histA = (int*)  alloc((size_t)NBLKA*NC*4);
  int*   prefA = (int*)  alloc((size_t)NC*NBLKA*4);
  int*   totalA= (int*)  alloc((size_t)NC*4);
  int*   cbase = (int*)  alloc((size_t)(NC+1)*4);
  int2*  csr   = (int2*) alloc((size_t)E*8);
  float* t2G   = (float*)alloc((size_t)B*480*4);
  int2*  ebufA = (int2*)h1;    // alias: dead before h1 written

  int cpb = (E + NBLKA - 1)/NBLKA;
  k_histA   <<<NBLKA, 256, 0, stream>>>(dst, histA, E, cpb);
  k_colscanA<<<NC, NBLKA, 0, stream>>>(histA, prefA, totalA);
  k_bscanA  <<<1,    256, 0, stream>>>(totalA, cbase);
  k_scatterA<<<NBLKA, 256, 0, stream>>>(src, dst, ew, prefA, cbase, ebufA, E, cpb);
  k_bucket8 <<<NC,  1024, 0, stream>>>(ebufA, cbase, dis, rs, csr, N);

  int gG = (N+127)/128;
  int gA = (N+3)/4;
  k_gemm1 <<<gG, 256, 0, stream>>>(w, z1, z2, embw, embz1, embz2, W0, dis, gx, N);
  k_agg32 <<<gA, 256, 0, stream>>>(gx, dis, rs, csr, b0, h1, N);
  k_gemm32<<<gG, 256, 0, stream>>>(h1, W1, dis, gx, N);
  k_agg32 <<<gA, 256, 0, stream>>>(gx, dis, rs, csr, b1, h2, N);
  k_gemm32<<<gG, 256, 0, stream>>>(h2, W2, dis, gx, N);
  k_agg32v<<<gA, 256, 0, stream>>>(gx, dis, rs, csr, b2, W3, h3, gv, N);

  k_sortpool<<<B, 256, 0, stream>>>(gv, dis, rs, csr, b3, h1, h2, h3, c1W, c1b, t2G, N);
  k_tail    <<<B/8, 256, 0, stream>>>(t2G, c2W, c2b, l1W, l1b, l2W, l2b, out);
}

// Round 9
// 668.818 us; speedup vs baseline: 3.5429x; 1.0346x over previous
//
#include <hip/hip_runtime.h>
#include <math.h>

#define NPG 100
#define KTOP 60
#define DLAT 97
#define NC 250          // coarse buckets (8 graphs = 800 nodes each)
#define NODESC 800      // nodes per coarse bucket
#define NBLKA 1024      // binning blocks

static __device__ __forceinline__ float dot4(float4 a, float4 b){
  return a.x*b.x + a.y*b.y + a.z*b.z + a.w*b.w;
}

// ---------------- prep: two-level atomic-free CSR build ----------------
__global__ __launch_bounds__(256) void k_histA(const int* __restrict__ dst, int* __restrict__ histA,
    int E, int cpb){
  __shared__ int h[NC];
  int blk = blockIdx.x, tid = threadIdx.x;
  if(tid < NC) h[tid] = 0;
  __syncthreads();
  int e0 = blk*cpb, e1 = min(e0+cpb, E);
  for(int e=e0+tid; e<e1; e+=256) atomicAdd(&h[dst[e]/NODESC], 1);
  __syncthreads();
  if(tid < NC) histA[blk*NC + tid] = h[tid];
}

__global__ __launch_bounds__(NBLKA) void k_colscanA(const int* __restrict__ histA,
    int* __restrict__ prefA, int* __restrict__ totalA){
  __shared__ int s[NBLKA];
  int c = blockIdx.x, t = threadIdx.x;
  int v = histA[t*NC + c];
  s[t] = v;
  __syncthreads();
  for(int off=1; off<NBLKA; off<<=1){
    int u = (t >= off) ? s[t-off] : 0;
    __syncthreads();
    s[t] += u;
    __syncthreads();
  }
  prefA[c*NBLKA + t] = s[t] - v;
  if(t == NBLKA-1) totalA[c] = s[t];
}

__global__ __launch_bounds__(256) void k_bscanA(const int* __restrict__ totalA, int* __restrict__ cbase){
  __shared__ int s[256];
  int t = threadIdx.x;
  int v = (t < NC) ? totalA[t] : 0;
  s[t] = v;
  __syncthreads();
  for(int off=1; off<256; off<<=1){
    int u = (t >= off) ? s[t-off] : 0;
    __syncthreads();
    s[t] += u;
    __syncthreads();
  }
  if(t < NC) cbase[t] = s[t] - v;
  if(t == 255) cbase[NC] = s[255];
}

__global__ __launch_bounds__(256) void k_scatterA(const int* __restrict__ src, const int* __restrict__ dst,
    const float* __restrict__ ew, const int* __restrict__ prefA, const int* __restrict__ cbase,
    int2* __restrict__ ebufA, int E, int cpb){
  __shared__ int cur[NC];
  int blk = blockIdx.x, tid = threadIdx.x;
  if(tid < NC) cur[tid] = prefA[tid*NBLKA + blk] + cbase[tid];
  __syncthreads();
  int e0 = blk*cpb, e1 = min(e0+cpb, E);
  for(int e=e0+tid; e<e1; e+=256){
    int d = dst[e];
    int c = d/NODESC;
    int dm = d - c*NODESC;
    int pos = atomicAdd(&cur[c], 1);          // LDS atomic
    ebufA[pos] = make_int2(src[e] | (dm<<18), __float_as_int(ew[e]));
  }
}

__global__ __launch_bounds__(1024) void k_bucket8(const int2* __restrict__ ebufA, const int* __restrict__ cbase,
    float* __restrict__ dis, int* __restrict__ rs, int2* __restrict__ csr, int N){
  __shared__ float degw[NODESC];
  __shared__ int cnt[NODESC];
  __shared__ int cur[NODESC];
  __shared__ int sc[1024];
  int c = blockIdx.x, tid = threadIdx.x;
  int n0 = c*NODESC;
  if(tid < NODESC){ degw[tid] = 0.f; cnt[tid] = 0; }
  __syncthreads();
  int e0 = cbase[c], e1 = cbase[c+1];
  for(int e=e0+tid; e<e1; e+=1024){
    int2 t = ebufA[e];
    int ld = ((unsigned)t.x)>>18;
    atomicAdd(&cnt[ld], 1);
    atomicAdd(&degw[ld], __int_as_float(t.y));
  }
  __syncthreads();
  if(tid < NODESC) dis[n0+tid] = rsqrtf(degw[tid] + 1.0f);
  sc[tid] = (tid < NODESC) ? cnt[tid] : 0;
  __syncthreads();
  for(int off=1; off<1024; off<<=1){
    int u = (tid >= off) ? sc[tid-off] : 0;
    __syncthreads();
    sc[tid] += u;
    __syncthreads();
  }
  if(tid < NODESC){
    int st = e0 + sc[tid] - cnt[tid];
    cur[tid] = st;
    rs[n0+tid] = st;
  }
  if(c == NC-1 && tid == 0) rs[N] = e1;
  __syncthreads();
  for(int e=e0+tid; e<e1; e+=1024){
    int2 t = ebufA[e];
    int ld = ((unsigned)t.x)>>18;
    int pos = atomicAdd(&cur[ld], 1);
    csr[pos] = make_int2((t.x & 0x3FFFF) << 7, t.y);   // src as BYTE offset (src*128)
  }
}

// ---------------- GEMMs (row-major out, pre-scaled by dis[n]) ----------------
__global__ __launch_bounds__(256) void k_gemm1(const int* __restrict__ wI, const int* __restrict__ z1I,
   const int* __restrict__ z2I,
   const float* __restrict__ embw, const float* __restrict__ embz1, const float* __restrict__ embz2,
   const float* __restrict__ W0, const float* __restrict__ dis, float* __restrict__ gx, int N){
  __shared__ __align__(16) float X[128][97];
  __shared__ __align__(16) float Ws[96*32];
  __shared__ int iw[128], i1[128], i2[128];
  int tid = threadIdx.x;
  int g0 = blockIdx.x*128;
  for(int i=tid;i<768;i+=256) ((float4*)Ws)[i] = ((const float4*)W0)[i];
  if(tid < 128){
    int gn = g0 + tid;
    bool ok = gn < N;
    iw[tid] = ok ? wI[gn]  : 0;
    i1[tid] = ok ? z1I[gn] : 0;
    i2[tid] = ok ? z2I[gn] : 0;
  }
  __syncthreads();
  for(int r=0;r<48;r++){
    int flat = r*256 + tid;
    int n = flat/96, c = flat - n*96;
    int gn = g0 + n;
    float val = 0.f;
    if(gn < N){
      if(c < 32)      val = embw [iw[n]*32 + c];
      else if(c < 64) val = embz1[i1[n]*32 + (c-32)];
      else            val = embz2[i2[n]*32 + (c-64)];
    }
    X[n][c] = val;
  }
  __syncthreads();
  int ng = tid>>3, chg = tid&7;
  float4 acc[4];
  #pragma unroll
  for(int j=0;j<4;j++) acc[j] = make_float4(0.f,0.f,0.f,0.f);
  #pragma unroll 4
  for(int i=0;i<96;i++){
    float4 wv = *(const float4*)&Ws[i*32 + chg*4];
    #pragma unroll
    for(int j=0;j<4;j++){
      float xv = X[ng*4+j][i];
      acc[j].x += xv*wv.x; acc[j].y += xv*wv.y; acc[j].z += xv*wv.z; acc[j].w += xv*wv.w;
    }
  }
  #pragma unroll
  for(int j=0;j<4;j++){
    int gn = g0 + ng*4 + j;
    if(gn < N){
      float dv = dis[gn];
      acc[j].x *= dv; acc[j].y *= dv; acc[j].z *= dv; acc[j].w *= dv;
      *(float4*)&gx[(size_t)gn*32 + chg*4] = acc[j];
    }
  }
}

__global__ __launch_bounds__(256) void k_gemm32(const float* __restrict__ xin, const float* __restrict__ W,
    const float* __restrict__ dis, float* __restrict__ gx, int N){
  __shared__ __align__(16) float X[128][33];
  __shared__ __align__(16) float Ws[32*32];
  int tid = threadIdx.x;
  int g0 = blockIdx.x*128;
  ((float4*)Ws)[tid] = ((const float4*)W)[tid];
  for(int r=0;r<4;r++){
    int f = r*256 + tid;
    int n = f>>3, c4 = f&7;
    int gn = g0 + n;
    float4 v = (gn < N) ? ((const float4*)(xin + (size_t)gn*32))[c4] : make_float4(0,0,0,0);
    float* xr = &X[n][c4*4];
    xr[0]=v.x; xr[1]=v.y; xr[2]=v.z; xr[3]=v.w;
  }
  __syncthreads();
  int ng = tid>>3, chg = tid&7;
  float4 acc[4];
  #pragma unroll
  for(int j=0;j<4;j++) acc[j] = make_float4(0.f,0.f,0.f,0.f);
  #pragma unroll 4
  for(int i=0;i<32;i++){
    float4 wv = *(const float4*)&Ws[i*32 + chg*4];
    #pragma unroll
    for(int j=0;j<4;j++){
      float xv = X[ng*4+j][i];
      acc[j].x += xv*wv.x; acc[j].y += xv*wv.y; acc[j].z += xv*wv.z; acc[j].w += xv*wv.w;
    }
  }
  #pragma unroll
  for(int j=0;j<4;j++){
    int gn = g0 + ng*4 + j;
    if(gn < N){
      float dv = dis[gn];
      acc[j].x *= dv; acc[j].y *= dv; acc[j].z *= dv; acc[j].w *= dv;
      *(float4*)&gx[(size_t)gn*32 + chg*4] = acc[j];
    }
  }
}

// ---------------- aggregation: wave/node, 8 edge-slots x 8 ch-groups, 2-deep pipeline ----------------
__global__ __launch_bounds__(256) void k_agg32(const float* __restrict__ g,
   const float* __restrict__ dis, const int* __restrict__ rs, const int2* __restrict__ csr,
   const float* __restrict__ bias, float* __restrict__ hout, int N){
  int wave = threadIdx.x >> 6;
  int lane = threadIdx.x & 63;
  int es = lane >> 3;
  int cg = lane & 7;
  int n = blockIdx.x*4 + wave;
  if(n >= N) return;
  int e0 = rs[n], e1 = rs[n+1];
  const char* gb = (const char*)g;
  int cgo = cg*16;
  float4 acc0 = make_float4(0.f,0.f,0.f,0.f);
  float4 acc1 = make_float4(0.f,0.f,0.f,0.f);
  int e = e0 + es;
  int2 p0 = (e   < e1) ? csr[e]   : make_int2(0,0);   // w=0 pad reads row 0: contributes 0
  int2 p1 = (e+8 < e1) ? csr[e+8] : make_int2(0,0);
  int iters2 = (e1 - e0 + 15) >> 4;
  for(int it=0; it<iters2; ++it){
    e += 16;
    int2 q0 = (e   < e1) ? csr[e]   : make_int2(0,0);
    int2 q1 = (e+8 < e1) ? csr[e+8] : make_int2(0,0);
    float4 v0 = *(const float4*)(gb + (p0.x + cgo));  // two independent rows in flight
    float4 v1 = *(const float4*)(gb + (p1.x + cgo));
    float w0 = __int_as_float(p0.y), w1 = __int_as_float(p1.y);
    acc0.x += w0*v0.x; acc0.y += w0*v0.y; acc0.z += w0*v0.z; acc0.w += w0*v0.w;
    acc1.x += w1*v1.x; acc1.y += w1*v1.y; acc1.z += w1*v1.z; acc1.w += w1*v1.w;
    p0 = q0; p1 = q1;
  }
  float4 acc = make_float4(acc0.x+acc1.x, acc0.y+acc1.y, acc0.z+acc1.z, acc0.w+acc1.w);
  #pragma unroll
  for(int off=8; off<64; off<<=1){
    acc.x += __shfl_xor(acc.x, off);
    acc.y += __shfl_xor(acc.y, off);
    acc.z += __shfl_xor(acc.z, off);
    acc.w += __shfl_xor(acc.w, off);
  }
  float4 self = ((const float4*)(g + (size_t)n*32))[cg];
  float dn = dis[n];
  float4 bv = ((const float4*)bias)[cg];
  if(es == 0){
    float4 o;
    o.x = tanhf(dn*(acc.x + self.x) + bv.x);
    o.y = tanhf(dn*(acc.y + self.y) + bv.y);
    o.z = tanhf(dn*(acc.z + self.z) + bv.z);
    o.w = tanhf(dn*(acc.w + self.w) + bv.w);
    ((float4*)(hout + (size_t)n*32))[cg] = o;
  }
}

// layer-3 variant: also emits gv[n] = (h3 . W3) * dis[n]  (fused gemmv)
__global__ __launch_bounds__(256) void k_agg32v(const float* __restrict__ g,
   const float* __restrict__ dis, const int* __restrict__ rs, const int2* __restrict__ csr,
   const float* __restrict__ bias, const float* __restrict__ W3,
   float* __restrict__ hout, float* __restrict__ gv, int N){
  int wave = threadIdx.x >> 6;
  int lane = threadIdx.x & 63;
  int es = lane >> 3;
  int cg = lane & 7;
  int n = blockIdx.x*4 + wave;
  if(n >= N) return;
  int e0 = rs[n], e1 = rs[n+1];
  const char* gb = (const char*)g;
  int cgo = cg*16;
  float4 acc0 = make_float4(0.f,0.f,0.f,0.f);
  float4 acc1 = make_float4(0.f,0.f,0.f,0.f);
  int e = e0 + es;
  int2 p0 = (e   < e1) ? csr[e]   : make_int2(0,0);
  int2 p1 = (e+8 < e1) ? csr[e+8] : make_int2(0,0);
  int iters2 = (e1 - e0 + 15) >> 4;
  for(int it=0; it<iters2; ++it){
    e += 16;
    int2 q0 = (e   < e1) ? csr[e]   : make_int2(0,0);
    int2 q1 = (e+8 < e1) ? csr[e+8] : make_int2(0,0);
    float4 v0 = *(const float4*)(gb + (p0.x + cgo));
    float4 v1 = *(const float4*)(gb + (p1.x + cgo));
    float w0 = __int_as_float(p0.y), w1 = __int_as_float(p1.y);
    acc0.x += w0*v0.x; acc0.y += w0*v0.y; acc0.z += w0*v0.z; acc0.w += w0*v0.w;
    acc1.x += w1*v1.x; acc1.y += w1*v1.y; acc1.z += w1*v1.z; acc1.w += w1*v1.w;
    p0 = q0; p1 = q1;
  }
  float4 acc = make_float4(acc0.x+acc1.x, acc0.y+acc1.y, acc0.z+acc1.z, acc0.w+acc1.w);
  #pragma unroll
  for(int off=8; off<64; off<<=1){
    acc.x += __shfl_xor(acc.x, off);
    acc.y += __shfl_xor(acc.y, off);
    acc.z += __shfl_xor(acc.z, off);
    acc.w += __shfl_xor(acc.w, off);
  }
  float4 self = ((const float4*)(g + (size_t)n*32))[cg];
  float dn = dis[n];
  float4 bv = ((const float4*)bias)[cg];
  if(es == 0){
    float4 o;
    o.x = tanhf(dn*(acc.x + self.x) + bv.x);
    o.y = tanhf(dn*(acc.y + self.y) + bv.y);
    o.z = tanhf(dn*(acc.z + self.z) + bv.z);
    o.w = tanhf(dn*(acc.w + self.w) + bv.w);
    ((float4*)(hout + (size_t)n*32))[cg] = o;
    float4 w3v = *(const float4*)&W3[cg*4];
    float s = dot4(o, w3v);
    s += __shfl_xor(s, 1);
    s += __shfl_xor(s, 2);
    s += __shfl_xor(s, 4);
    if(cg == 0) gv[n] = s*dn;
  }
}

// ---------------- kA: fused agg1 + sort + gather + conv1 + maxpool -> t2G[B][16][30] ----------------
__global__ __launch_bounds__(256) void k_sortpool(const float* __restrict__ gv,
  const float* __restrict__ dis, const int* __restrict__ rs, const int2* __restrict__ csr,
  const float* __restrict__ b3,
  const float* __restrict__ h1,const float* __restrict__ h2,const float* __restrict__ h3,
  const float* __restrict__ c1W,const float* __restrict__ c1b,
  float* __restrict__ t2G, int N){
  __shared__ float v[128];
  __shared__ int ord[KTOP];
  __shared__ __align__(16) float xk[KTOP][100];
  __shared__ __align__(16) float c1Ws[16*100];
  __shared__ __align__(16) float t2s[480];
  int b = blockIdx.x, tid = threadIdx.x;
  int g0 = b*NPG;
  for(int i=tid;i<16*97;i+=256){ int o=i/97, d=i-o*97; c1Ws[o*100+d]=c1W[i]; }
  // fused agg1: h4 for this graph's 100 nodes (gv is globally complete)
  if(tid < 100){
    int n = g0 + tid;
    float acc = gv[n];
    int e0 = rs[n], e1 = rs[n+1];
    for(int e=e0;e<e1;e++){
      int2 p = csr[e];
      acc += __int_as_float(p.y)*gv[((unsigned)p.x)>>7];
    }
    v[tid] = tanhf(dis[n]*acc + b3[0]);
  }
  __syncthreads();
  // stable descending rank == argsort(-v) stable
  if(tid < 100){
    float vi = v[tid];
    int rank = 0;
    for(int j=0;j<100;j++){
      float vj = v[j];
      rank += (vj > vi) || (vj == vi && j < tid);
    }
    if(rank < KTOP) ord[rank] = tid;
  }
  __syncthreads();
  for(int idx=tid; idx<KTOP*DLAT; idx+=256){
    int k = idx/DLAT, d = idx - k*DLAT;
    int nk = ord[k];
    float val;
    if(d < 96){
      const float* hsrc = (d<32) ? h1 : (d<64) ? h2 : h3;
      val = hsrc[(size_t)(g0+nk)*32 + (d&31)];
    } else val = v[nk];
    xk[k][d] = val;
  }
  __syncthreads();
  {
    int og = tid & 7, j = tid >> 3;
    if(j < 30){
      int k0 = 2*j, k1 = 2*j+1;
      float a00=0.f, a01=0.f, a10=0.f, a11=0.f;
      for(int d=0; d<96; d+=4){
        float4 w0 = *(const float4*)&c1Ws[og*100 + d];
        float4 w1 = *(const float4*)&c1Ws[(og+8)*100 + d];
        float4 x0 = *(const float4*)&xk[k0][d];
        float4 x1 = *(const float4*)&xk[k1][d];
        a00 += dot4(x0, w0); a01 += dot4(x1, w0);
        a10 += dot4(x0, w1); a11 += dot4(x1, w1);
      }
      {
        float w0 = c1Ws[og*100 + 96], w1 = c1Ws[(og+8)*100 + 96];
        float x0 = xk[k0][96], x1 = xk[k1][96];
        a00 += x0*w0; a01 += x1*w0;
        a10 += x0*w1; a11 += x1*w1;
      }
      float b0v = c1b[og], b1v = c1b[og+8];
      float r0 = fmaxf(fmaxf(a00+b0v,0.f), fmaxf(a01+b0v,0.f));
      float r1 = fmaxf(fmaxf(a10+b1v,0.f), fmaxf(a11+b1v,0.f));
      t2s[og*30 + j] = r0;
      t2s[(og+8)*30 + j] = r1;
    }
  }
  __syncthreads();
  if(tid < 120) ((float4*)&t2G[(size_t)b*480])[tid] = ((const float4*)t2s)[tid];
}

// ---------------- kB: conv2 + l1 + l2, 8 graphs per block ----------------
__global__ __launch_bounds__(256) void k_tail(const float* __restrict__ t2G,
  const float* __restrict__ c2W,const float* __restrict__ c2b,
  const float* __restrict__ l1W,const float* __restrict__ l1b,
  const float* __restrict__ l2W,const float* __restrict__ l2b,
  float* __restrict__ out){
  __shared__ __align__(16) float t2s[8*480];
  __shared__ __align__(16) float c2Ws[2560];
  __shared__ __align__(16) float flat[8][832];
  __shared__ __align__(16) float o1s[8][128];
  int bG = blockIdx.x, tid = threadIdx.x;
  for(int i=tid; i<960; i+=256) ((float4*)t2s)[i] = ((const float4*)(t2G + (size_t)bG*8*480))[i];
  for(int i=tid; i<640; i+=256) ((float4*)c2Ws)[i] = ((const float4*)c2W)[i];
  __syncthreads();
  {
    int g = tid >> 5, oc = tid & 31;
    float acc[26];
    #pragma unroll
    for(int p=0;p<26;p++) acc[p]=0.f;
    for(int ic=0; ic<16; ic++){
      const float* trow = &t2s[g*480 + ic*30];
      float t[30];
      #pragma unroll
      for(int p=0;p<30;p++) t[p] = trow[p];
      const float* wr = &c2Ws[(oc*16 + ic)*5];
      float w0=wr[0], w1=wr[1], w2=wr[2], w3=wr[3], w4=wr[4];
      #pragma unroll
      for(int p=0;p<26;p++)
        acc[p] += t[p]*w0 + t[p+1]*w1 + t[p+2]*w2 + t[p+3]*w3 + t[p+4]*w4;
    }
    float bb = c2b[oc];
    #pragma unroll
    for(int p=0;p<26;p++) flat[g][oc*26+p] = fmaxf(acc[p]+bb, 0.f);
  }
  __syncthreads();
  {
    int j = tid & 127, gq = tid >> 7;
    float acc0=0.f, acc1=0.f, acc2=0.f, acc3=0.f;
    const float* f0 = flat[gq*4+0];
    const float* f1 = flat[gq*4+1];
    const float* f2 = flat[gq*4+2];
    const float* f3 = flat[gq*4+3];
    for(int i4=0; i4<208; i4++){
      int i = i4*4;
      float w0 = l1W[(size_t)i*128 + j];
      float w1 = l1W[(size_t)(i+1)*128 + j];
      float w2 = l1W[(size_t)(i+2)*128 + j];
      float w3 = l1W[(size_t)(i+3)*128 + j];
      float4 a0 = *(const float4*)&f0[i];
      float4 a1 = *(const float4*)&f1[i];
      float4 a2 = *(const float4*)&f2[i];
      float4 a3 = *(const float4*)&f3[i];
      acc0 += a0.x*w0 + a0.y*w1 + a0.z*w2 + a0.w*w3;
      acc1 += a1.x*w0 + a1.y*w1 + a1.z*w2 + a1.w*w3;
      acc2 += a2.x*w0 + a2.y*w1 + a2.z*w2 + a2.w*w3;
      acc3 += a3.x*w0 + a3.y*w1 + a3.z*w2 + a3.w*w3;
    }
    o1s[gq*4+0][j] = acc0;
    o1s[gq*4+1][j] = acc1;
    o1s[gq*4+2][j] = acc2;
    o1s[gq*4+3][j] = acc3;
  }
  __syncthreads();
  {
    int g = tid >> 5, jj = tid & 31;
    float s = 0.f;
    #pragma unroll
    for(int q=0;q<4;q++){
      int j = jj + 32*q;
      float r = fmaxf(o1s[g][j] + l1b[j], 0.f);
      s += r * l2W[j];
    }
    #pragma unroll
    for(int off=16; off>0; off>>=1) s += __shfl_xor(s, off);
    if(jj == 0) out[bG*8 + g] = s + l2b[0];
  }
}

// ---------------- launch ----------------
extern "C" void kernel_launch(void* const* d_in, const int* in_sizes, int n_in,
                              void* d_out, int out_size, void* d_ws, size_t ws_size,
                              hipStream_t stream){
  (void)n_in; (void)out_size; (void)ws_size;
  const int*   z1    = (const int*)  d_in[0];
  const int*   z2    = (const int*)  d_in[1];
  const int*   w     = (const int*)  d_in[2];
  const int*   eidx  = (const int*)  d_in[3];
  const float* ew    = (const float*)d_in[5];
  const float* embw  = (const float*)d_in[6];
  const float* embz1 = (const float*)d_in[7];
  const float* embz2 = (const float*)d_in[8];
  const float* W0    = (const float*)d_in[9];
  const float* b0    = (const float*)d_in[10];
  const float* W1    = (const float*)d_in[11];
  const float* b1    = (const float*)d_in[12];
  const float* W2    = (const float*)d_in[13];
  const float* b2    = (const float*)d_in[14];
  const float* W3    = (const float*)d_in[15];
  const float* b3    = (const float*)d_in[16];
  const float* c1W   = (const float*)d_in[17];
  const float* c1b   = (const float*)d_in[18];
  const float* c2W   = (const float*)d_in[19];
  const float* c2b   = (const float*)d_in[20];
  const float* l1W   = (const float*)d_in[21];
  const float* l1b   = (const float*)d_in[22];
  const float* l2W   = (const float*)d_in[23];
  const float* l2b   = (const float*)d_in[24];
  float* out = (float*)d_out;

  int N = in_sizes[0];
  int E = in_sizes[3]/2;
  int B = N/NPG;
  const int* src = eidx;
  const int* dst = eidx + E;

  char* p = (char*)d_ws;
  auto alloc = [&](size_t bytes)->char*{
    char* r = p;
    p += (bytes + 255) & ~(size_t)255;
    return r;
  };
  float* h1    = (float*)alloc((size_t)N*32*4);
  float* h2    = (float*)alloc((size_t)N*32*4);
  float* h3    = (float*)alloc((size_t)N*32*4);
  float* gv    = (float*)alloc((size_t)N*4);
  float* gx    = (float*)alloc((size_t)N*32*4);
  float* dis   = (float*)alloc((size_t)N*4);
  int*   rs    = (int*)  alloc((size_t)(N+1)*4);
  int*   histA = (int*)  alloc((size_t)NBLKA*NC*4);
  int*   prefA = (int*)  alloc((size_t)NC*NBLKA*4);
  int*   totalA= (int*)  alloc((size_t)NC*4);
  int*   cbase = (int*)  alloc((size_t)(NC+1)*4);
  int2*  csr   = (int2*) alloc((size_t)E*8);
  float* t2G   = (float*)alloc((size_t)B*480*4);
  int2*  ebufA = (int2*)h1;    // alias: dead before h1 written

  int cpb = (E + NBLKA - 1)/NBLKA;
  k_histA   <<<NBLKA, 256, 0, stream>>>(dst, histA, E, cpb);
  k_colscanA<<<NC, NBLKA, 0, stream>>>(histA, prefA, totalA);
  k_bscanA  <<<1,    256, 0, stream>>>(totalA, cbase);
  k_scatterA<<<NBLKA, 256, 0, stream>>>(src, dst, ew, prefA, cbase, ebufA, E, cpb);
  k_bucket8 <<<NC,  1024, 0, stream>>>(ebufA, cbase, dis, rs, csr, N);

  int gG = (N+127)/128;
  int gA = (N+3)/4;
  k_gemm1 <<<gG, 256, 0, stream>>>(w, z1, z2, embw, embz1, embz2, W0, dis, gx, N);
  k_agg32 <<<gA, 256, 0, stream>>>(gx, dis, rs, csr, b0, h1, N);
  k_gemm32<<<gG, 256, 0, stream>>>(h1, W1, dis, gx, N);
  k_agg32 <<<gA, 256, 0, stream>>>(gx, dis, rs, csr, b1, h2, N);
  k_gemm32<<<gG, 256, 0, stream>>>(h2, W2, dis, gx, N);
  k_agg32v<<<gA, 256, 0, stream>>>(gx, dis, rs, csr, b2, W3, h3, gv, N);

  k_sortpool<<<B, 256, 0, stream>>>(gv, dis, rs, csr, b3, h1, h2, h3, c1W, c1b, t2G, N);
  k_tail    <<<B/8, 256, 0, stream>>>(t2G, c2W, c2b, l1W, l1b, l2W, l2b, out);
}